// Round 1
// baseline (951.848 us; speedup 1.0000x reference)
//
#include <hip/hip_runtime.h>
#include <hip/hip_bf16.h>

// GAT 2-layer forward on MI355X.
// Strategy: CSR-by-dst build (int atomics only) + pull-based aggregation with
// online softmax (no float atomics, no segment max/sum arrays).
// Workspace usage ~74 MB.

#define F_IN 500
#define HEADS 8
#define HID 8
#define HD 64   // HEADS*HID
#define CLS 3
#define NEG 0.2f
#define EPSV 1e-16f

#define G1_NODES 128
#define G1_KT 50
#define G1_KTP 51   // padded stride: row-stride 8*51=408 mod 32 banks -> conflict-free
#define SCB 512

// ---------- edge_index dtype detection (int32 vs int64 little-endian) ----------
__global__ void k_detect(const int* ei, int* flag) {
    // If data is int64 (values < 2^31), every odd int32 word is a zero high-word.
    int z = 0;
    for (int i = 1; i < 16; i += 2) z += (ei[i] == 0) ? 1 : 0;
    *flag = (z == 8) ? 1 : 0;
}

__device__ inline int ld_edge(const void* ei, long idx, int is64) {
    return is64 ? (int)((const long long*)ei)[idx] : ((const int*)ei)[idx];
}

// ---------- Layer-1 GEMM: h1[N,64] = x[N,500] @ W1[500,64] (f32) ----------
__global__ __launch_bounds__(256) void k_gemm1(const float* __restrict__ x,
        const float* __restrict__ W1, float* __restrict__ h1, int N) {
    __shared__ float xs[G1_NODES * G1_KTP];
    int t = threadIdx.x;
    int n0 = blockIdx.x * G1_NODES;
    int c4 = (t & 15) * 4;   // output column group (4 cols)
    int g = t >> 4;          // node subgroup 0..15 (8 nodes each)
    float acc[8][4];
#pragma unroll
    for (int i = 0; i < 8; i++)
#pragma unroll
        for (int j = 0; j < 4; j++) acc[i][j] = 0.f;

    for (int k0 = 0; k0 < F_IN; k0 += G1_KT) {
        __syncthreads();
        for (int idx = t; idx < G1_NODES * G1_KT; idx += 256) {
            int r = idx / G1_KT, cc = idx - r * G1_KT;
            int n = n0 + r;
            xs[r * G1_KTP + cc] = (n < N) ? x[(long)n * F_IN + k0 + cc] : 0.f;
        }
        __syncthreads();
        for (int kk = 0; kk < G1_KT; kk++) {
            float4 w = *reinterpret_cast<const float4*>(&W1[(k0 + kk) * HD + c4]);
#pragma unroll
            for (int i = 0; i < 8; i++) {
                float xv = xs[(g * 8 + i) * G1_KTP + kk];
                acc[i][0] += xv * w.x; acc[i][1] += xv * w.y;
                acc[i][2] += xv * w.z; acc[i][3] += xv * w.w;
            }
        }
    }
#pragma unroll
    for (int i = 0; i < 8; i++) {
        int n = n0 + g * 8 + i;
        if (n < N) {
            float4 v = make_float4(acc[i][0], acc[i][1], acc[i][2], acc[i][3]);
            *reinterpret_cast<float4*>(&h1[(long)n * HD + c4]) = v;
        }
    }
}

// ---------- per-node attention logits, layer 1 ----------
__global__ void k_attlogits1(const float* __restrict__ h1,
        const float* __restrict__ asrc, const float* __restrict__ adst,
        float* __restrict__ als, float* __restrict__ ald, int N) {
    int t = blockIdx.x * 256 + threadIdx.x;
    if (t >= N * HEADS) return;
    int h = t & 7;
    const float* hp = &h1[(long)(t >> 3) * HD + h * HID];
    float s1 = 0.f, s2 = 0.f;
#pragma unroll
    for (int d = 0; d < HID; d++) {
        float v = hp[d];
        s1 += v * asrc[h * HID + d];
        s2 += v * adst[h * HID + d];
    }
    als[t] = s1; ald[t] = s2;
}

// ---------- CSR build ----------
__global__ void k_deg(const void* ei, int E, int N, int* deg, const int* flag) {
    int i = blockIdx.x * 256 + threadIdx.x;
    int tot = E + N;
    if (i >= tot) return;
    int is64 = *flag;
    int dst = (i < E) ? ld_edge(ei, (long)E + i, is64) : (i - E);
    atomicAdd(&deg[dst], 1);
}

__global__ __launch_bounds__(SCB) void k_scan1(const int* deg, int* rowptr, int* bsum, int N) {
    __shared__ int s[SCB];
    int tid = threadIdx.x;
    int i = blockIdx.x * SCB + tid;
    int v = (i < N) ? deg[i] : 0;
    s[tid] = v;
    __syncthreads();
    for (int off = 1; off < SCB; off <<= 1) {
        int tv = (tid >= off) ? s[tid - off] : 0;
        __syncthreads();
        s[tid] += tv;
        __syncthreads();
    }
    if (i < N) rowptr[i] = s[tid] - v;       // exclusive within chunk
    if (tid == SCB - 1) bsum[blockIdx.x] = s[tid];
}

__global__ void k_scan2(int* bsum, int* rowptr, int nb, int N) {
    int run = 0;
    for (int i = 0; i < nb; i++) { int v = bsum[i]; bsum[i] = run; run += v; }
    rowptr[N] = run;   // == E+N
}

__global__ void k_scan3(int* rowptr, const int* bsum, int N) {
    int i = blockIdx.x * SCB + threadIdx.x;
    if (i < N) rowptr[i] += bsum[blockIdx.x];
}

__global__ void k_fill(const void* ei, int E, int N, const int* rowptr,
                       int* cursor, int* csr, const int* flag) {
    int i = blockIdx.x * 256 + threadIdx.x;
    int tot = E + N;
    if (i >= tot) return;
    int is64 = *flag;
    int src, dst;
    if (i < E) { src = ld_edge(ei, i, is64); dst = ld_edge(ei, (long)E + i, is64); }
    else { src = dst = i - E; }
    int pos = rowptr[dst] + atomicAdd(&cursor[dst], 1);
    csr[pos] = src;
}

// ---------- Layer-1 pull aggregation + bias + ELU (wave per node) ----------
__global__ __launch_bounds__(256) void k_agg1(const int* __restrict__ rowptr,
        const int* __restrict__ csr, const float* __restrict__ h1,
        const float* __restrict__ als, const float* __restrict__ ald,
        const float* __restrict__ b1, float* __restrict__ hact, int N) {
    int n = blockIdx.x * 4 + (threadIdx.x >> 6);
    if (n >= N) return;
    int lane = threadIdx.x & 63;
    int h = lane >> 3;
    float aldv = ald[n * HEADS + h];
    int rs = rowptr[n], re = rowptr[n + 1];
    float m = -__builtin_inff(), sum = 0.f, acc = 0.f;
    for (int j = rs; j < re; j++) {
        int s = csr[j];
        float e = als[s * HEADS + h] + aldv;
        e = (e >= 0.f) ? e : NEG * e;
        float nm = fmaxf(m, e);
        float sc = __expf(m - nm);   // 0 on first iter (m=-inf), 1 if max unchanged
        float p = __expf(e - nm);
        float hv = h1[(long)s * HD + lane];
        sum = sum * sc + p;
        acc = acc * sc + p * hv;
        m = nm;
    }
    float o = acc / (sum + EPSV) + b1[lane];
    o = (o > 0.f) ? o : __expf(o) - 1.f;   // ELU
    hact[(long)n * HD + lane] = o;
}

// ---------- Layer-2 GEMM [N,64]x[64,3] + logits (wave per node) ----------
__global__ __launch_bounds__(256) void k_gemm2(const float* __restrict__ hact,
        const float* __restrict__ W2, const float* __restrict__ as2,
        const float* __restrict__ ad2, float* __restrict__ h2,
        float* __restrict__ als2, float* __restrict__ ald2, int N) {
    int n = blockIdx.x * 4 + (threadIdx.x >> 6);
    if (n >= N) return;
    int lane = threadIdx.x & 63;
    float hv = hact[(long)n * HD + lane];
    float p0 = hv * W2[lane * CLS + 0];
    float p1 = hv * W2[lane * CLS + 1];
    float p2 = hv * W2[lane * CLS + 2];
#pragma unroll
    for (int off = 32; off > 0; off >>= 1) {
        p0 += __shfl_down(p0, off);
        p1 += __shfl_down(p1, off);
        p2 += __shfl_down(p2, off);
    }
    if (lane == 0) {
        h2[n * CLS + 0] = p0; h2[n * CLS + 1] = p1; h2[n * CLS + 2] = p2;
        als2[n] = p0 * as2[0] + p1 * as2[1] + p2 * as2[2];
        ald2[n] = p0 * ad2[0] + p1 * ad2[1] + p2 * ad2[2];
    }
}

// ---------- Layer-2 pull aggregation + bias + log_softmax ----------
__global__ __launch_bounds__(256) void k_agg2(const int* __restrict__ rowptr,
        const int* __restrict__ csr, const float* __restrict__ h2,
        const float* __restrict__ als2v, const float* __restrict__ ald2v,
        const float* __restrict__ b2, float* __restrict__ out, int N) {
    int n = blockIdx.x * 4 + (threadIdx.x >> 6);
    if (n >= N) return;
    int lane = threadIdx.x & 63;
    float aldv = ald2v[n];
    int rs = rowptr[n], re = rowptr[n + 1];
    float m = -__builtin_inff(), sum = 0.f, a0 = 0.f, a1 = 0.f, a2 = 0.f;
    for (int j = rs + lane; j < re; j += 64) {
        int s = csr[j];
        float e = als2v[s] + aldv;
        e = (e >= 0.f) ? e : NEG * e;
        float nm = fmaxf(m, e);
        float sc = __expf(m - nm);
        float p = __expf(e - nm);
        sum = sum * sc + p;
        a0 = a0 * sc + p * h2[s * CLS + 0];
        a1 = a1 * sc + p * h2[s * CLS + 1];
        a2 = a2 * sc + p * h2[s * CLS + 2];
        m = nm;
    }
    // merge lanes: global max, rescale, sum
    float M = m;
#pragma unroll
    for (int off = 1; off < 64; off <<= 1) M = fmaxf(M, __shfl_xor(M, off));
    float sc = __expf(m - M);   // m=-inf lanes contribute 0
    sum *= sc; a0 *= sc; a1 *= sc; a2 *= sc;
#pragma unroll
    for (int off = 1; off < 64; off <<= 1) {
        sum += __shfl_xor(sum, off);
        a0 += __shfl_xor(a0, off);
        a1 += __shfl_xor(a1, off);
        a2 += __shfl_xor(a2, off);
    }
    if (lane == 0) {
        float d = sum + EPSV;
        float v0 = a0 / d + b2[0], v1 = a1 / d + b2[1], v2 = a2 / d + b2[2];
        float mx = fmaxf(v0, fmaxf(v1, v2));
        float se = __expf(v0 - mx) + __expf(v1 - mx) + __expf(v2 - mx);
        float ls = mx + __logf(se);
        out[n * CLS + 0] = v0; out[n * CLS + 1] = v1; out[n * CLS + 2] = v2;
        long o2 = (long)N * CLS;
        out[o2 + n * CLS + 0] = v0 - ls;
        out[o2 + n * CLS + 1] = v1 - ls;
        out[o2 + n * CLS + 2] = v2 - ls;
    }
}

extern "C" void kernel_launch(void* const* d_in, const int* in_sizes, int n_in,
                              void* d_out, int out_size, void* d_ws, size_t ws_size,
                              hipStream_t stream) {
    const float* x   = (const float*)d_in[0];
    const void*  ei  = d_in[1];
    const float* W1  = (const float*)d_in[2];
    const float* as1 = (const float*)d_in[3];
    const float* ad1 = (const float*)d_in[4];
    const float* b1  = (const float*)d_in[5];
    const float* W2  = (const float*)d_in[6];
    const float* as2 = (const float*)d_in[7];
    const float* ad2 = (const float*)d_in[8];
    const float* b2  = (const float*)d_in[9];
    int N = in_sizes[0] / F_IN;
    int E = in_sizes[1] / 2;
    int tot = E + N;

    char* w = (char*)d_ws;
    auto alloc = [&](size_t bytes) -> char* {
        char* p = w; w += (bytes + 255) & ~size_t(255); return p;
    };
    float* h1     = (float*)alloc((size_t)N * HD * 4);
    float* hact   = (float*)alloc((size_t)N * HD * 4);
    float* als1   = (float*)alloc((size_t)N * HEADS * 4);
    float* ald1   = (float*)alloc((size_t)N * HEADS * 4);
    int*   rowptr = (int*)alloc((size_t)(N + 1) * 4);
    int*   deg    = (int*)alloc((size_t)N * 4);
    int*   cursor = (int*)alloc((size_t)N * 4);
    int nb = (N + SCB - 1) / SCB;
    int*   bsum   = (int*)alloc((size_t)nb * 4);
    int*   csr    = (int*)alloc((size_t)tot * 4);
    float* h2     = (float*)alloc((size_t)N * CLS * 4);
    float* als2   = (float*)alloc((size_t)N * 4);
    float* ald2   = (float*)alloc((size_t)N * 4);
    int*   flag   = (int*)alloc(256);

    hipMemsetAsync(deg, 0, (size_t)N * 4, stream);
    hipMemsetAsync(cursor, 0, (size_t)N * 4, stream);

    k_detect<<<1, 1, 0, stream>>>((const int*)ei, flag);
    k_gemm1<<<(N + G1_NODES - 1) / G1_NODES, 256, 0, stream>>>(x, W1, h1, N);
    k_attlogits1<<<(N * HEADS + 255) / 256, 256, 0, stream>>>(h1, as1, ad1, als1, ald1, N);
    k_deg<<<(tot + 255) / 256, 256, 0, stream>>>(ei, E, N, deg, flag);
    k_scan1<<<nb, SCB, 0, stream>>>(deg, rowptr, bsum, N);
    k_scan2<<<1, 1, 0, stream>>>(bsum, rowptr, nb, N);
    k_scan3<<<nb, SCB, 0, stream>>>(rowptr, bsum, N);
    k_fill<<<(tot + 255) / 256, 256, 0, stream>>>(ei, E, N, rowptr, cursor, csr, flag);
    k_agg1<<<(N + 3) / 4, 256, 0, stream>>>(rowptr, csr, h1, als1, ald1, b1, hact, N);
    k_gemm2<<<(N + 3) / 4, 256, 0, stream>>>(hact, W2, as2, ad2, h2, als2, ald2, N);
    k_agg2<<<(N + 3) / 4, 256, 0, stream>>>(rowptr, csr, h2, als2, ald2, b2, (float*)d_out, N);
}

// Round 2
// 816.131 us; speedup vs baseline: 1.1663x; 1.1663x over previous
//
#include <hip/hip_runtime.h>
#include <hip/hip_bf16.h>

// GAT 2-layer forward on MI355X.
// CSR-by-dst build (int atomics only) + pull-based aggregation.
// Layer-1 agg: two-pass (per-head max/denom via 8-edge-parallel pass, then
// unrolled weighted-accumulate pass gathering bf16 h1).

#define F_IN 500
#define HEADS 8
#define HID 8
#define HD 64   // HEADS*HID
#define CLS 3
#define NEG 0.2f
#define EPSV 1e-16f

#define G1_NODES 128
#define G1_KT 50
#define G1_KTP 51
#define SCB 512

// ---------- edge_index dtype detection (int32 vs int64 little-endian) ----------
__global__ void k_detect(const int* ei, int* flag) {
    int z = 0;
    for (int i = 1; i < 16; i += 2) z += (ei[i] == 0) ? 1 : 0;
    *flag = (z == 8) ? 1 : 0;
}

__device__ inline int ld_edge(const void* ei, long idx, int is64) {
    return is64 ? (int)((const long long*)ei)[idx] : ((const int*)ei)[idx];
}

// ---------- Layer-1 GEMM: h1[N,64] = x[N,500] @ W1[500,64] (f32) ----------
__global__ __launch_bounds__(256) void k_gemm1(const float* __restrict__ x,
        const float* __restrict__ W1, float* __restrict__ h1, int N) {
    __shared__ float xs[G1_NODES * G1_KTP];
    int t = threadIdx.x;
    int n0 = blockIdx.x * G1_NODES;
    int c4 = (t & 15) * 4;
    int g = t >> 4;
    float acc[8][4];
#pragma unroll
    for (int i = 0; i < 8; i++)
#pragma unroll
        for (int j = 0; j < 4; j++) acc[i][j] = 0.f;

    for (int k0 = 0; k0 < F_IN; k0 += G1_KT) {
        __syncthreads();
        for (int idx = t; idx < G1_NODES * G1_KT; idx += 256) {
            int r = idx / G1_KT, cc = idx - r * G1_KT;
            int n = n0 + r;
            xs[r * G1_KTP + cc] = (n < N) ? x[(long)n * F_IN + k0 + cc] : 0.f;
        }
        __syncthreads();
        for (int kk = 0; kk < G1_KT; kk++) {
            float4 w = *reinterpret_cast<const float4*>(&W1[(k0 + kk) * HD + c4]);
#pragma unroll
            for (int i = 0; i < 8; i++) {
                float xv = xs[(g * 8 + i) * G1_KTP + kk];
                acc[i][0] += xv * w.x; acc[i][1] += xv * w.y;
                acc[i][2] += xv * w.z; acc[i][3] += xv * w.w;
            }
        }
    }
#pragma unroll
    for (int i = 0; i < 8; i++) {
        int n = n0 + g * 8 + i;
        if (n < N) {
            float4 v = make_float4(acc[i][0], acc[i][1], acc[i][2], acc[i][3]);
            *reinterpret_cast<float4*>(&h1[(long)n * HD + c4]) = v;
        }
    }
}

// ---------- per-node attention logits (f32 h1) + bf16 copy of h1 ----------
__global__ void k_attlogits1(const float* __restrict__ h1,
        const float* __restrict__ asrc, const float* __restrict__ adst,
        float* __restrict__ als, float* __restrict__ ald,
        ushort* __restrict__ h1b, int N) {
    int t = blockIdx.x * 256 + threadIdx.x;
    if (t >= N * HEADS) return;
    int h = t & 7;
    const float* hp = &h1[(long)t * HID];   // t = node*8+h -> node*64 + h*8 = t*8
    float s1 = 0.f, s2 = 0.f;
    uint w[4];
#pragma unroll
    for (int d = 0; d < 4; d++) {
        float v0 = hp[2 * d], v1 = hp[2 * d + 1];
        s1 += v0 * asrc[h * HID + 2 * d] + v1 * asrc[h * HID + 2 * d + 1];
        s2 += v0 * adst[h * HID + 2 * d] + v1 * adst[h * HID + 2 * d + 1];
        __hip_bfloat16 b0 = __float2bfloat16(v0);
        __hip_bfloat16 b1 = __float2bfloat16(v1);
        w[d] = (uint)*(unsigned short*)&b0 | ((uint)*(unsigned short*)&b1 << 16);
    }
    als[t] = s1; ald[t] = s2;
    *reinterpret_cast<uint4*>(&h1b[(long)t * 8]) = make_uint4(w[0], w[1], w[2], w[3]);
}

// ---------- CSR build ----------
__global__ void k_deg(const void* ei, int E, int N, int* deg, const int* flag) {
    int i = blockIdx.x * 256 + threadIdx.x;
    int tot = E + N;
    if (i >= tot) return;
    int is64 = *flag;
    int dst = (i < E) ? ld_edge(ei, (long)E + i, is64) : (i - E);
    atomicAdd(&deg[dst], 1);
}

__global__ __launch_bounds__(SCB) void k_scan1(const int* deg, int* rowptr, int* bsum, int N) {
    __shared__ int s[SCB];
    int tid = threadIdx.x;
    int i = blockIdx.x * SCB + tid;
    int v = (i < N) ? deg[i] : 0;
    s[tid] = v;
    __syncthreads();
    for (int off = 1; off < SCB; off <<= 1) {
        int tv = (tid >= off) ? s[tid - off] : 0;
        __syncthreads();
        s[tid] += tv;
        __syncthreads();
    }
    if (i < N) rowptr[i] = s[tid] - v;
    if (tid == SCB - 1) bsum[blockIdx.x] = s[tid];
}

__global__ void k_scan2(int* bsum, int* rowptr, int nb, int N) {
    int run = 0;
    for (int i = 0; i < nb; i++) { int v = bsum[i]; bsum[i] = run; run += v; }
    rowptr[N] = run;
}

__global__ void k_scan3(int* rowptr, const int* bsum, int N) {
    int i = blockIdx.x * SCB + threadIdx.x;
    if (i < N) rowptr[i] += bsum[blockIdx.x];
}

__global__ void k_fill(const void* ei, int E, int N, const int* rowptr,
                       int* cursor, int* csr, const int* flag) {
    int i = blockIdx.x * 256 + threadIdx.x;
    int tot = E + N;
    if (i >= tot) return;
    int is64 = *flag;
    int src, dst;
    if (i < E) { src = ld_edge(ei, i, is64); dst = ld_edge(ei, (long)E + i, is64); }
    else { src = dst = i - E; }
    int pos = rowptr[dst] + atomicAdd(&cursor[dst], 1);
    csr[pos] = src;
}

// ---------- Layer-1 pull aggregation + bias + ELU (wave per node, 2-pass) ----------
__global__ __launch_bounds__(256) void k_agg1(const int* __restrict__ rowptr,
        const int* __restrict__ csr, const ushort* __restrict__ h1b,
        const float* __restrict__ als, const float* __restrict__ ald,
        const float* __restrict__ b1, float* __restrict__ hact, int N) {
    int n = blockIdx.x * 4 + (threadIdx.x >> 6);
    if (n >= N) return;
    int lane = threadIdx.x & 63;
    int rs = rowptr[n], re = rowptr[n + 1];

    // ---- pass A: per-head (max, denom). lane = jsub*8 + h
    int hA = lane & 7, jsub = lane >> 3;
    float aldA = ald[n * HEADS + hA];
    float m = -1e30f, sum = 0.f;
    for (int j = rs + jsub; j < re; j += 8) {
        int s = csr[j];
        float e = als[s * HEADS + hA] + aldA;
        e = (e >= 0.f) ? e : NEG * e;
        float nm = fmaxf(m, e);
        float sc = __expf(m - nm);
        sum = sum * sc + __expf(e - nm);
        m = nm;
    }
#pragma unroll
    for (int off = 8; off < 64; off <<= 1) {
        float m2 = __shfl_xor(m, off);
        float s2 = __shfl_xor(sum, off);
        float nm = fmaxf(m, m2);
        sum = sum * __expf(m - nm) + s2 * __expf(m2 - nm);
        m = nm;
    }
    // lanes with hA==k all hold head-k results; lane k (k<8) has head k.
    int hB = lane >> 3;
    float mB = __shfl(m, hB);
    float dB = __shfl(sum, hB);
    float aldB = __shfl(aldA, hB);
    float inv = 1.f / (dB + EPSV);

    // ---- pass B: acc = sum_j exp(e_j - mB) * h1b[s_j], unrolled x4
    float a0 = 0.f, a1 = 0.f, a2 = 0.f, a3 = 0.f;
    int j = rs;
    for (; j + 4 <= re; j += 4) {
        int s0 = csr[j], s1 = csr[j + 1], s2 = csr[j + 2], s3 = csr[j + 3];
        float e0 = als[s0 * HEADS + hB] + aldB;
        float e1 = als[s1 * HEADS + hB] + aldB;
        float e2 = als[s2 * HEADS + hB] + aldB;
        float e3 = als[s3 * HEADS + hB] + aldB;
        ushort u0 = h1b[(long)s0 * HD + lane];
        ushort u1 = h1b[(long)s1 * HD + lane];
        ushort u2 = h1b[(long)s2 * HD + lane];
        ushort u3 = h1b[(long)s3 * HD + lane];
        e0 = (e0 >= 0.f) ? e0 : NEG * e0;
        e1 = (e1 >= 0.f) ? e1 : NEG * e1;
        e2 = (e2 >= 0.f) ? e2 : NEG * e2;
        e3 = (e3 >= 0.f) ? e3 : NEG * e3;
        float p0 = __expf(e0 - mB);
        float p1 = __expf(e1 - mB);
        float p2 = __expf(e2 - mB);
        float p3 = __expf(e3 - mB);
        a0 += p0 * __bfloat162float(*(const __hip_bfloat16*)&u0);
        a1 += p1 * __bfloat162float(*(const __hip_bfloat16*)&u1);
        a2 += p2 * __bfloat162float(*(const __hip_bfloat16*)&u2);
        a3 += p3 * __bfloat162float(*(const __hip_bfloat16*)&u3);
    }
    for (; j < re; j++) {
        int s0 = csr[j];
        float e0 = als[s0 * HEADS + hB] + aldB;
        e0 = (e0 >= 0.f) ? e0 : NEG * e0;
        float p0 = __expf(e0 - mB);
        ushort u0 = h1b[(long)s0 * HD + lane];
        a0 += p0 * __bfloat162float(*(const __hip_bfloat16*)&u0);
    }
    float o = ((a0 + a1) + (a2 + a3)) * inv + b1[lane];
    o = (o > 0.f) ? o : __expf(o) - 1.f;   // ELU
    hact[(long)n * HD + lane] = o;
}

// ---------- Layer-2 GEMM [N,64]x[64,3] + logits (wave per node) ----------
__global__ __launch_bounds__(256) void k_gemm2(const float* __restrict__ hact,
        const float* __restrict__ W2, const float* __restrict__ as2,
        const float* __restrict__ ad2, float* __restrict__ h2,
        float* __restrict__ als2, float* __restrict__ ald2, int N) {
    int n = blockIdx.x * 4 + (threadIdx.x >> 6);
    if (n >= N) return;
    int lane = threadIdx.x & 63;
    float hv = hact[(long)n * HD + lane];
    float p0 = hv * W2[lane * CLS + 0];
    float p1 = hv * W2[lane * CLS + 1];
    float p2 = hv * W2[lane * CLS + 2];
#pragma unroll
    for (int off = 32; off > 0; off >>= 1) {
        p0 += __shfl_down(p0, off);
        p1 += __shfl_down(p1, off);
        p2 += __shfl_down(p2, off);
    }
    if (lane == 0) {
        h2[n * CLS + 0] = p0; h2[n * CLS + 1] = p1; h2[n * CLS + 2] = p2;
        als2[n] = p0 * as2[0] + p1 * as2[1] + p2 * as2[2];
        ald2[n] = p0 * ad2[0] + p1 * ad2[1] + p2 * ad2[2];
    }
}

// ---------- Layer-2 pull aggregation + bias + log_softmax ----------
__global__ __launch_bounds__(256) void k_agg2(const int* __restrict__ rowptr,
        const int* __restrict__ csr, const float* __restrict__ h2,
        const float* __restrict__ als2v, const float* __restrict__ ald2v,
        const float* __restrict__ b2, float* __restrict__ out, int N) {
    int n = blockIdx.x * 4 + (threadIdx.x >> 6);
    if (n >= N) return;
    int lane = threadIdx.x & 63;
    float aldv = ald2v[n];
    int rs = rowptr[n], re = rowptr[n + 1];
    float m = -1e30f, sum = 0.f, a0 = 0.f, a1 = 0.f, a2 = 0.f;
    for (int j = rs + lane; j < re; j += 64) {
        int s = csr[j];
        float e = als2v[s] + aldv;
        e = (e >= 0.f) ? e : NEG * e;
        float nm = fmaxf(m, e);
        float sc = __expf(m - nm);
        float p = __expf(e - nm);
        sum = sum * sc + p;
        a0 = a0 * sc + p * h2[s * CLS + 0];
        a1 = a1 * sc + p * h2[s * CLS + 1];
        a2 = a2 * sc + p * h2[s * CLS + 2];
        m = nm;
    }
    float M = m;
#pragma unroll
    for (int off = 1; off < 64; off <<= 1) M = fmaxf(M, __shfl_xor(M, off));
    float sc = __expf(m - M);
    sum *= sc; a0 *= sc; a1 *= sc; a2 *= sc;
#pragma unroll
    for (int off = 1; off < 64; off <<= 1) {
        sum += __shfl_xor(sum, off);
        a0 += __shfl_xor(a0, off);
        a1 += __shfl_xor(a1, off);
        a2 += __shfl_xor(a2, off);
    }
    if (lane == 0) {
        float d = sum + EPSV;
        float v0 = a0 / d + b2[0], v1 = a1 / d + b2[1], v2 = a2 / d + b2[2];
        float mx = fmaxf(v0, fmaxf(v1, v2));
        float se = __expf(v0 - mx) + __expf(v1 - mx) + __expf(v2 - mx);
        float ls = mx + __logf(se);
        out[n * CLS + 0] = v0; out[n * CLS + 1] = v1; out[n * CLS + 2] = v2;
        long o2 = (long)N * CLS;
        out[o2 + n * CLS + 0] = v0 - ls;
        out[o2 + n * CLS + 1] = v1 - ls;
        out[o2 + n * CLS + 2] = v2 - ls;
    }
}

extern "C" void kernel_launch(void* const* d_in, const int* in_sizes, int n_in,
                              void* d_out, int out_size, void* d_ws, size_t ws_size,
                              hipStream_t stream) {
    const float* x   = (const float*)d_in[0];
    const void*  ei  = d_in[1];
    const float* W1  = (const float*)d_in[2];
    const float* as1 = (const float*)d_in[3];
    const float* ad1 = (const float*)d_in[4];
    const float* b1  = (const float*)d_in[5];
    const float* W2  = (const float*)d_in[6];
    const float* as2 = (const float*)d_in[7];
    const float* ad2 = (const float*)d_in[8];
    const float* b2  = (const float*)d_in[9];
    int N = in_sizes[0] / F_IN;
    int E = in_sizes[1] / 2;
    int tot = E + N;

    char* w = (char*)d_ws;
    auto alloc = [&](size_t bytes) -> char* {
        char* p = w; w += (bytes + 255) & ~size_t(255); return p;
    };
    float*  h1     = (float*)alloc((size_t)N * HD * 4);
    ushort* h1b    = (ushort*)alloc((size_t)N * HD * 2);
    float*  hact   = (float*)alloc((size_t)N * HD * 4);
    float*  als1   = (float*)alloc((size_t)N * HEADS * 4);
    float*  ald1   = (float*)alloc((size_t)N * HEADS * 4);
    int*    rowptr = (int*)alloc((size_t)(N + 1) * 4);
    int*    deg    = (int*)alloc((size_t)N * 4);
    int*    cursor = (int*)alloc((size_t)N * 4);
    int nb = (N + SCB - 1) / SCB;
    int*    bsum   = (int*)alloc((size_t)nb * 4);
    int*    csr    = (int*)alloc((size_t)tot * 4);
    float*  h2     = (float*)alloc((size_t)N * CLS * 4);
    float*  als2   = (float*)alloc((size_t)N * 4);
    float*  ald2   = (float*)alloc((size_t)N * 4);
    int*    flag   = (int*)alloc(256);

    hipMemsetAsync(deg, 0, (size_t)N * 4, stream);
    hipMemsetAsync(cursor, 0, (size_t)N * 4, stream);

    k_detect<<<1, 1, 0, stream>>>((const int*)ei, flag);
    k_gemm1<<<(N + G1_NODES - 1) / G1_NODES, 256, 0, stream>>>(x, W1, h1, N);
    k_attlogits1<<<(N * HEADS + 255) / 256, 256, 0, stream>>>(h1, as1, ad1, als1, ald1, h1b, N);
    k_deg<<<(tot + 255) / 256, 256, 0, stream>>>(ei, E, N, deg, flag);
    k_scan1<<<nb, SCB, 0, stream>>>(deg, rowptr, bsum, N);
    k_scan2<<<1, 1, 0, stream>>>(bsum, rowptr, nb, N);
    k_scan3<<<nb, SCB, 0, stream>>>(rowptr, bsum, N);
    k_fill<<<(tot + 255) / 256, 256, 0, stream>>>(ei, E, N, rowptr, cursor, csr, flag);
    k_agg1<<<(N + 3) / 4, 256, 0, stream>>>(rowptr, csr, h1b, als1, ald1, b1, hact, N);
    k_gemm2<<<(N + 3) / 4, 256, 0, stream>>>(hact, W2, as2, ad2, h2, als2, ald2, N);
    k_agg2<<<(N + 3) / 4, 256, 0, stream>>>(rowptr, csr, h2, als2, ald2, b2, (float*)d_out, N);
}

// Round 3
// 646.907 us; speedup vs baseline: 1.4714x; 1.2616x over previous
//
#include <hip/hip_runtime.h>
#include <hip/hip_bf16.h>

// GAT 2-layer forward on MI355X.
// CSR-by-dst build (int atomics only) + pull-based aggregation.
// GEMM1: LDS-free bf16 MFMA (16x16x32), A-fragments loaded straight from
// global x (f32 -> bf16 in-register), B from a pre-transposed zero-padded
// bf16 W1 buffer.

#define F_IN 500
#define HEADS 8
#define HID 8
#define HD 64   // HEADS*HID
#define CLS 3
#define NEG 0.2f
#define EPSV 1e-16f
#define KPAD 512
#define SCB 512

typedef __attribute__((ext_vector_type(8))) short short8v;   // 8 bf16
typedef __attribute__((ext_vector_type(4))) float f32x4;

__device__ inline short bfs(float v) {
    __hip_bfloat16 b = __float2bfloat16(v);
    return *(short*)&b;
}

// ---------- edge_index dtype detection (int32 vs int64 little-endian) ----------
__global__ void k_detect(const int* ei, int* flag) {
    int z = 0;
    for (int i = 1; i < 16; i += 2) z += (ei[i] == 0) ? 1 : 0;
    *flag = (z == 8) ? 1 : 0;
}

__device__ inline int ld_edge(const void* ei, long idx, int is64) {
    return is64 ? (int)((const long long*)ei)[idx] : ((const int*)ei)[idx];
}

// ---------- W1 -> bf16, transposed [c][k] with k zero-padded to 512 ----------
__global__ void k_prepW(const float* __restrict__ W1, ushort* __restrict__ W1b) {
    int i = blockIdx.x * 256 + threadIdx.x;
    if (i >= HD * KPAD) return;
    int c = i >> 9, k = i & (KPAD - 1);
    float v = (k < F_IN) ? W1[k * HD + c] : 0.f;
    __hip_bfloat16 b = __float2bfloat16(v);
    W1b[i] = *(ushort*)&b;
}

// ---------- Layer-1 GEMM: h1[N,64] = x[N,500] @ W1[500,64], bf16 MFMA ----------
// Block: 256 threads = 4 waves; each wave: 16 rows x 64 cols.
// A-frag: lane l holds x[row(l&15)][k0 + (l>>4)*8 + j], j=0..7 (two float4 loads).
// B-frag: lane l holds W1[k0+(l>>4)*8+j][c0 + (l&15)] from W1b[c][k].
// D: row=(l>>4)*4+r, col=l&15.
__global__ __launch_bounds__(256) void k_gemm1(const float* __restrict__ x,
        const ushort* __restrict__ W1b, float* __restrict__ h1, int N) {
    int lane = threadIdx.x & 63;
    int w = threadIdx.x >> 6;
    int l16 = lane & 15, oct = lane >> 4;
    int rowb = blockIdx.x * 64 + w * 16;
    int row = rowb + l16;
    int rowc = (row < N) ? row : (N - 1);
    const float* xr = x + (long)rowc * F_IN;

    f32x4 acc0 = {0.f, 0.f, 0.f, 0.f};
    f32x4 acc1 = {0.f, 0.f, 0.f, 0.f};
    f32x4 acc2 = {0.f, 0.f, 0.f, 0.f};
    f32x4 acc3 = {0.f, 0.f, 0.f, 0.f};

    const ushort* Bl = W1b + (size_t)l16 * KPAD + oct * 8;   // + c*16*KPAD + k0

#pragma unroll
    for (int ks = 0; ks < 15; ++ks) {
        const int k0 = ks * 32;
        short8v b0 = *reinterpret_cast<const short8v*>(Bl + k0);
        short8v b1 = *reinterpret_cast<const short8v*>(Bl + 16 * KPAD + k0);
        short8v b2 = *reinterpret_cast<const short8v*>(Bl + 32 * KPAD + k0);
        short8v b3 = *reinterpret_cast<const short8v*>(Bl + 48 * KPAD + k0);
        float4 x0 = *reinterpret_cast<const float4*>(xr + k0 + oct * 8);
        float4 x1 = *reinterpret_cast<const float4*>(xr + k0 + oct * 8 + 4);
        short8v a;
        a[0] = bfs(x0.x); a[1] = bfs(x0.y); a[2] = bfs(x0.z); a[3] = bfs(x0.w);
        a[4] = bfs(x1.x); a[5] = bfs(x1.y); a[6] = bfs(x1.z); a[7] = bfs(x1.w);
        acc0 = __builtin_amdgcn_mfma_f32_16x16x32_bf16(a, b0, acc0, 0, 0, 0);
        acc1 = __builtin_amdgcn_mfma_f32_16x16x32_bf16(a, b1, acc1, 0, 0, 0);
        acc2 = __builtin_amdgcn_mfma_f32_16x16x32_bf16(a, b2, acc2, 0, 0, 0);
        acc3 = __builtin_amdgcn_mfma_f32_16x16x32_bf16(a, b3, acc3, 0, 0, 0);
    }
    {   // tail k0 = 480, valid k < 500 (W1b zero-padded so B loads are clean)
        const int k0 = 480;
        int kb = k0 + oct * 8;
        short8v a;
#pragma unroll
        for (int j = 0; j < 8; ++j)
            a[j] = bfs((kb + j < F_IN) ? xr[kb + j] : 0.f);
        short8v b0 = *reinterpret_cast<const short8v*>(Bl + k0);
        short8v b1 = *reinterpret_cast<const short8v*>(Bl + 16 * KPAD + k0);
        short8v b2 = *reinterpret_cast<const short8v*>(Bl + 32 * KPAD + k0);
        short8v b3 = *reinterpret_cast<const short8v*>(Bl + 48 * KPAD + k0);
        acc0 = __builtin_amdgcn_mfma_f32_16x16x32_bf16(a, b0, acc0, 0, 0, 0);
        acc1 = __builtin_amdgcn_mfma_f32_16x16x32_bf16(a, b1, acc1, 0, 0, 0);
        acc2 = __builtin_amdgcn_mfma_f32_16x16x32_bf16(a, b2, acc2, 0, 0, 0);
        acc3 = __builtin_amdgcn_mfma_f32_16x16x32_bf16(a, b3, acc3, 0, 0, 0);
    }
#pragma unroll
    for (int r = 0; r < 4; ++r) {
        int rr = rowb + oct * 4 + r;
        if (rr < N) {
            float* hp = h1 + (long)rr * HD + l16;
            hp[0]  = acc0[r];
            hp[16] = acc1[r];
            hp[32] = acc2[r];
            hp[48] = acc3[r];
        }
    }
}

// ---------- per-node attention logits (f32 h1) + bf16 copy of h1 ----------
__global__ void k_attlogits1(const float* __restrict__ h1,
        const float* __restrict__ asrc, const float* __restrict__ adst,
        float* __restrict__ als, float* __restrict__ ald,
        ushort* __restrict__ h1b, int N) {
    int t = blockIdx.x * 256 + threadIdx.x;
    if (t >= N * HEADS) return;
    int h = t & 7;
    const float* hp = &h1[(long)t * HID];
    float s1 = 0.f, s2 = 0.f;
    uint w[4];
#pragma unroll
    for (int d = 0; d < 4; d++) {
        float v0 = hp[2 * d], v1 = hp[2 * d + 1];
        s1 += v0 * asrc[h * HID + 2 * d] + v1 * asrc[h * HID + 2 * d + 1];
        s2 += v0 * adst[h * HID + 2 * d] + v1 * adst[h * HID + 2 * d + 1];
        __hip_bfloat16 b0 = __float2bfloat16(v0);
        __hip_bfloat16 b1 = __float2bfloat16(v1);
        w[d] = (uint)*(unsigned short*)&b0 | ((uint)*(unsigned short*)&b1 << 16);
    }
    als[t] = s1; ald[t] = s2;
    *reinterpret_cast<uint4*>(&h1b[(long)t * 8]) = make_uint4(w[0], w[1], w[2], w[3]);
}

// ---------- CSR build ----------
__global__ void k_deg(const void* ei, int E, int N, int* deg, const int* flag) {
    int i = blockIdx.x * 256 + threadIdx.x;
    int tot = E + N;
    if (i >= tot) return;
    int is64 = *flag;
    int dst = (i < E) ? ld_edge(ei, (long)E + i, is64) : (i - E);
    atomicAdd(&deg[dst], 1);
}

__global__ __launch_bounds__(SCB) void k_scan1(const int* deg, int* rowptr, int* bsum, int N) {
    __shared__ int s[SCB];
    int tid = threadIdx.x;
    int i = blockIdx.x * SCB + tid;
    int v = (i < N) ? deg[i] : 0;
    s[tid] = v;
    __syncthreads();
    for (int off = 1; off < SCB; off <<= 1) {
        int tv = (tid >= off) ? s[tid - off] : 0;
        __syncthreads();
        s[tid] += tv;
        __syncthreads();
    }
    if (i < N) rowptr[i] = s[tid] - v;
    if (tid == SCB - 1) bsum[blockIdx.x] = s[tid];
}

__global__ void k_scan2(int* bsum, int* rowptr, int nb, int N) {
    int run = 0;
    for (int i = 0; i < nb; i++) { int v = bsum[i]; bsum[i] = run; run += v; }
    rowptr[N] = run;
}

__global__ void k_scan3(int* rowptr, const int* bsum, int N) {
    int i = blockIdx.x * SCB + threadIdx.x;
    if (i < N) rowptr[i] += bsum[blockIdx.x];
}

__global__ void k_fill(const void* ei, int E, int N, const int* rowptr,
                       int* cursor, int* csr, const int* flag) {
    int i = blockIdx.x * 256 + threadIdx.x;
    int tot = E + N;
    if (i >= tot) return;
    int is64 = *flag;
    int src, dst;
    if (i < E) { src = ld_edge(ei, i, is64); dst = ld_edge(ei, (long)E + i, is64); }
    else { src = dst = i - E; }
    int pos = rowptr[dst] + atomicAdd(&cursor[dst], 1);
    csr[pos] = src;
}

// ---------- Layer-1 pull aggregation + bias + ELU (wave per node, 2-pass) ----------
__global__ __launch_bounds__(256) void k_agg1(const int* __restrict__ rowptr,
        const int* __restrict__ csr, const ushort* __restrict__ h1b,
        const float* __restrict__ als, const float* __restrict__ ald,
        const float* __restrict__ b1, float* __restrict__ hact, int N) {
    int n = blockIdx.x * 4 + (threadIdx.x >> 6);
    if (n >= N) return;
    int lane = threadIdx.x & 63;
    int rs = rowptr[n], re = rowptr[n + 1];

    // ---- pass A: per-head (max, denom). lane = jsub*8 + h
    int hA = lane & 7, jsub = lane >> 3;
    float aldA = ald[n * HEADS + hA];
    float m = -1e30f, sum = 0.f;
    for (int j = rs + jsub; j < re; j += 8) {
        int s = csr[j];
        float e = als[s * HEADS + hA] + aldA;
        e = (e >= 0.f) ? e : NEG * e;
        float nm = fmaxf(m, e);
        float sc = __expf(m - nm);
        sum = sum * sc + __expf(e - nm);
        m = nm;
    }
#pragma unroll
    for (int off = 8; off < 64; off <<= 1) {
        float m2 = __shfl_xor(m, off);
        float s2 = __shfl_xor(sum, off);
        float nm = fmaxf(m, m2);
        sum = sum * __expf(m - nm) + s2 * __expf(m2 - nm);
        m = nm;
    }
    int hB = lane >> 3;
    float mB = __shfl(m, hB);
    float dB = __shfl(sum, hB);
    float aldB = __shfl(aldA, hB);
    float inv = 1.f / (dB + EPSV);

    // ---- pass B: acc = sum_j exp(e_j - mB) * h1b[s_j], unrolled x4
    float a0 = 0.f, a1 = 0.f, a2 = 0.f, a3 = 0.f;
    int j = rs;
    for (; j + 4 <= re; j += 4) {
        int s0 = csr[j], s1 = csr[j + 1], s2 = csr[j + 2], s3 = csr[j + 3];
        float e0 = als[s0 * HEADS + hB] + aldB;
        float e1 = als[s1 * HEADS + hB] + aldB;
        float e2 = als[s2 * HEADS + hB] + aldB;
        float e3 = als[s3 * HEADS + hB] + aldB;
        ushort u0 = h1b[(long)s0 * HD + lane];
        ushort u1 = h1b[(long)s1 * HD + lane];
        ushort u2 = h1b[(long)s2 * HD + lane];
        ushort u3 = h1b[(long)s3 * HD + lane];
        e0 = (e0 >= 0.f) ? e0 : NEG * e0;
        e1 = (e1 >= 0.f) ? e1 : NEG * e1;
        e2 = (e2 >= 0.f) ? e2 : NEG * e2;
        e3 = (e3 >= 0.f) ? e3 : NEG * e3;
        float p0 = __expf(e0 - mB);
        float p1 = __expf(e1 - mB);
        float p2 = __expf(e2 - mB);
        float p3 = __expf(e3 - mB);
        a0 += p0 * __bfloat162float(*(const __hip_bfloat16*)&u0);
        a1 += p1 * __bfloat162float(*(const __hip_bfloat16*)&u1);
        a2 += p2 * __bfloat162float(*(const __hip_bfloat16*)&u2);
        a3 += p3 * __bfloat162float(*(const __hip_bfloat16*)&u3);
    }
    for (; j < re; j++) {
        int s0 = csr[j];
        float e0 = als[s0 * HEADS + hB] + aldB;
        e0 = (e0 >= 0.f) ? e0 : NEG * e0;
        float p0 = __expf(e0 - mB);
        ushort u0 = h1b[(long)s0 * HD + lane];
        a0 += p0 * __bfloat162float(*(const __hip_bfloat16*)&u0);
    }
    float o = ((a0 + a1) + (a2 + a3)) * inv + b1[lane];
    o = (o > 0.f) ? o : __expf(o) - 1.f;   // ELU
    hact[(long)n * HD + lane] = o;
}

// ---------- Layer-2 GEMM [N,64]x[64,3] + logits (wave per node) ----------
__global__ __launch_bounds__(256) void k_gemm2(const float* __restrict__ hact,
        const float* __restrict__ W2, const float* __restrict__ as2,
        const float* __restrict__ ad2, float* __restrict__ h2,
        float* __restrict__ als2, float* __restrict__ ald2, int N) {
    int n = blockIdx.x * 4 + (threadIdx.x >> 6);
    if (n >= N) return;
    int lane = threadIdx.x & 63;
    float hv = hact[(long)n * HD + lane];
    float p0 = hv * W2[lane * CLS + 0];
    float p1 = hv * W2[lane * CLS + 1];
    float p2 = hv * W2[lane * CLS + 2];
#pragma unroll
    for (int off = 32; off > 0; off >>= 1) {
        p0 += __shfl_down(p0, off);
        p1 += __shfl_down(p1, off);
        p2 += __shfl_down(p2, off);
    }
    if (lane == 0) {
        h2[n * CLS + 0] = p0; h2[n * CLS + 1] = p1; h2[n * CLS + 2] = p2;
        als2[n] = p0 * as2[0] + p1 * as2[1] + p2 * as2[2];
        ald2[n] = p0 * ad2[0] + p1 * ad2[1] + p2 * ad2[2];
    }
}

// ---------- Layer-2 pull aggregation + bias + log_softmax ----------
__global__ __launch_bounds__(256) void k_agg2(const int* __restrict__ rowptr,
        const int* __restrict__ csr, const float* __restrict__ h2,
        const float* __restrict__ als2v, const float* __restrict__ ald2v,
        const float* __restrict__ b2, float* __restrict__ out, int N) {
    int n = blockIdx.x * 4 + (threadIdx.x >> 6);
    if (n >= N) return;
    int lane = threadIdx.x & 63;
    float aldv = ald2v[n];
    int rs = rowptr[n], re = rowptr[n + 1];
    float m = -1e30f, sum = 0.f, a0 = 0.f, a1 = 0.f, a2 = 0.f;
    for (int j = rs + lane; j < re; j += 64) {
        int s = csr[j];
        float e = als2v[s] + aldv;
        e = (e >= 0.f) ? e : NEG * e;
        float nm = fmaxf(m, e);
        float sc = __expf(m - nm);
        float p = __expf(e - nm);
        sum = sum * sc + p;
        a0 = a0 * sc + p * h2[s * CLS + 0];
        a1 = a1 * sc + p * h2[s * CLS + 1];
        a2 = a2 * sc + p * h2[s * CLS + 2];
        m = nm;
    }
    float M = m;
#pragma unroll
    for (int off = 1; off < 64; off <<= 1) M = fmaxf(M, __shfl_xor(M, off));
    float sc = __expf(m - M);
    sum *= sc; a0 *= sc; a1 *= sc; a2 *= sc;
#pragma unroll
    for (int off = 1; off < 64; off <<= 1) {
        sum += __shfl_xor(sum, off);
        a0 += __shfl_xor(a0, off);
        a1 += __shfl_xor(a1, off);
        a2 += __shfl_xor(a2, off);
    }
    if (lane == 0) {
        float d = sum + EPSV;
        float v0 = a0 / d + b2[0], v1 = a1 / d + b2[1], v2 = a2 / d + b2[2];
        float mx = fmaxf(v0, fmaxf(v1, v2));
        float se = __expf(v0 - mx) + __expf(v1 - mx) + __expf(v2 - mx);
        float ls = mx + __logf(se);
        out[n * CLS + 0] = v0; out[n * CLS + 1] = v1; out[n * CLS + 2] = v2;
        long o2 = (long)N * CLS;
        out[o2 + n * CLS + 0] = v0 - ls;
        out[o2 + n * CLS + 1] = v1 - ls;
        out[o2 + n * CLS + 2] = v2 - ls;
    }
}

extern "C" void kernel_launch(void* const* d_in, const int* in_sizes, int n_in,
                              void* d_out, int out_size, void* d_ws, size_t ws_size,
                              hipStream_t stream) {
    const float* x   = (const float*)d_in[0];
    const void*  ei  = d_in[1];
    const float* W1  = (const float*)d_in[2];
    const float* as1 = (const float*)d_in[3];
    const float* ad1 = (const float*)d_in[4];
    const float* b1  = (const float*)d_in[5];
    const float* W2  = (const float*)d_in[6];
    const float* as2 = (const float*)d_in[7];
    const float* ad2 = (const float*)d_in[8];
    const float* b2  = (const float*)d_in[9];
    int N = in_sizes[0] / F_IN;
    int E = in_sizes[1] / 2;
    int tot = E + N;

    char* w = (char*)d_ws;
    auto alloc = [&](size_t bytes) -> char* {
        char* p = w; w += (bytes + 255) & ~size_t(255); return p;
    };
    float*  h1     = (float*)alloc((size_t)N * HD * 4);
    ushort* h1b    = (ushort*)alloc((size_t)N * HD * 2);
    float*  hact   = (float*)alloc((size_t)N * HD * 4);
    float*  als1   = (float*)alloc((size_t)N * HEADS * 4);
    float*  ald1   = (float*)alloc((size_t)N * HEADS * 4);
    int*    rowptr = (int*)alloc((size_t)(N + 1) * 4);
    int*    deg    = (int*)alloc((size_t)N * 4);
    int*    cursor = (int*)alloc((size_t)N * 4);
    int nb = (N + SCB - 1) / SCB;
    int*    bsum   = (int*)alloc((size_t)nb * 4);
    int*    csr    = (int*)alloc((size_t)tot * 4);
    float*  h2     = (float*)alloc((size_t)N * CLS * 4);
    float*  als2   = (float*)alloc((size_t)N * 4);
    float*  ald2   = (float*)alloc((size_t)N * 4);
    ushort* W1b    = (ushort*)alloc((size_t)HD * KPAD * 2);
    int*    flag   = (int*)alloc(256);

    hipMemsetAsync(deg, 0, (size_t)N * 4, stream);
    hipMemsetAsync(cursor, 0, (size_t)N * 4, stream);

    k_detect<<<1, 1, 0, stream>>>((const int*)ei, flag);
    k_prepW<<<(HD * KPAD + 255) / 256, 256, 0, stream>>>(W1, W1b);
    k_gemm1<<<(N + 63) / 64, 256, 0, stream>>>(x, W1b, h1, N);
    k_attlogits1<<<(N * HEADS + 255) / 256, 256, 0, stream>>>(h1, as1, ad1, als1, ald1, h1b, N);
    k_deg<<<(tot + 255) / 256, 256, 0, stream>>>(ei, E, N, deg, flag);
    k_scan1<<<nb, SCB, 0, stream>>>(deg, rowptr, bsum, N);
    k_scan2<<<1, 1, 0, stream>>>(bsum, rowptr, nb, N);
    k_scan3<<<nb, SCB, 0, stream>>>(rowptr, bsum, N);
    k_fill<<<(tot + 255) / 256, 256, 0, stream>>>(ei, E, N, rowptr, cursor, csr, flag);
    k_agg1<<<(N + 3) / 4, 256, 0, stream>>>(rowptr, csr, h1b, als1, ald1, b1, hact, N);
    k_gemm2<<<(N + 3) / 4, 256, 0, stream>>>(hact, W2, as2, ad2, h2, als2, ald2, N);
    k_agg2<<<(N + 3) / 4, 256, 0, stream>>>(rowptr, csr, h2, als2, ald2, b2, (float*)d_out, N);
}

// Round 4
// 522.140 us; speedup vs baseline: 1.8230x; 1.2390x over previous
//
#include <hip/hip_runtime.h>
#include <hip/hip_bf16.h>

// GAT 2-layer forward on MI355X.
// CSR-by-dst build via two-level counting sort (no global atomics, dense
// writes) + pull-based aggregation with per-head two-pass softmax.
// GEMM1: LDS-free bf16 MFMA (16x16x32) straight from global x.

#define F_IN 500
#define HEADS 8
#define HID 8
#define HD 64   // HEADS*HID
#define CLS 3
#define NEG 0.2f
#define EPSV 1e-16f
#define KPAD 512
#define SCB 512

#define NBLK_H 128     // blocks in hist/scatter passes
#define NBKT_MAX 3136  // >= ceil(N/32)

typedef __attribute__((ext_vector_type(8))) short short8v;   // 8 bf16
typedef __attribute__((ext_vector_type(4))) float f32x4;

__device__ inline short bfs(float v) {
    __hip_bfloat16 b = __float2bfloat16(v);
    return *(short*)&b;
}

// ---------- edge_index dtype detection (int32 vs int64 little-endian) ----------
__global__ void k_detect(const int* ei, int* flag) {
    int z = 0;
    for (int i = 1; i < 16; i += 2) z += (ei[i] == 0) ? 1 : 0;
    *flag = (z == 8) ? 1 : 0;
}

__device__ inline int ld_edge(const void* ei, long idx, int is64) {
    return is64 ? (int)((const long long*)ei)[idx] : ((const int*)ei)[idx];
}

// ---------- W1 -> bf16, transposed [c][k] with k zero-padded to 512 ----------
__global__ void k_prepW(const float* __restrict__ W1, ushort* __restrict__ W1b) {
    int i = blockIdx.x * 256 + threadIdx.x;
    if (i >= HD * KPAD) return;
    int c = i >> 9, k = i & (KPAD - 1);
    float v = (k < F_IN) ? W1[k * HD + c] : 0.f;
    __hip_bfloat16 b = __float2bfloat16(v);
    W1b[i] = *(ushort*)&b;
}

// ---------- Layer-1 GEMM: h1[N,64] = x[N,500] @ W1[500,64], bf16 MFMA ----------
__global__ __launch_bounds__(256) void k_gemm1(const float* __restrict__ x,
        const ushort* __restrict__ W1b, float* __restrict__ h1, int N) {
    int lane = threadIdx.x & 63;
    int w = threadIdx.x >> 6;
    int l16 = lane & 15, oct = lane >> 4;
    int rowb = blockIdx.x * 64 + w * 16;
    int row = rowb + l16;
    int rowc = (row < N) ? row : (N - 1);
    const float* xr = x + (long)rowc * F_IN;

    f32x4 acc0 = {0.f, 0.f, 0.f, 0.f};
    f32x4 acc1 = {0.f, 0.f, 0.f, 0.f};
    f32x4 acc2 = {0.f, 0.f, 0.f, 0.f};
    f32x4 acc3 = {0.f, 0.f, 0.f, 0.f};

    const ushort* Bl = W1b + (size_t)l16 * KPAD + oct * 8;

#pragma unroll
    for (int ks = 0; ks < 15; ++ks) {
        const int k0 = ks * 32;
        short8v b0 = *reinterpret_cast<const short8v*>(Bl + k0);
        short8v b1 = *reinterpret_cast<const short8v*>(Bl + 16 * KPAD + k0);
        short8v b2 = *reinterpret_cast<const short8v*>(Bl + 32 * KPAD + k0);
        short8v b3 = *reinterpret_cast<const short8v*>(Bl + 48 * KPAD + k0);
        float4 x0 = *reinterpret_cast<const float4*>(xr + k0 + oct * 8);
        float4 x1 = *reinterpret_cast<const float4*>(xr + k0 + oct * 8 + 4);
        short8v a;
        a[0] = bfs(x0.x); a[1] = bfs(x0.y); a[2] = bfs(x0.z); a[3] = bfs(x0.w);
        a[4] = bfs(x1.x); a[5] = bfs(x1.y); a[6] = bfs(x1.z); a[7] = bfs(x1.w);
        acc0 = __builtin_amdgcn_mfma_f32_16x16x32_bf16(a, b0, acc0, 0, 0, 0);
        acc1 = __builtin_amdgcn_mfma_f32_16x16x32_bf16(a, b1, acc1, 0, 0, 0);
        acc2 = __builtin_amdgcn_mfma_f32_16x16x32_bf16(a, b2, acc2, 0, 0, 0);
        acc3 = __builtin_amdgcn_mfma_f32_16x16x32_bf16(a, b3, acc3, 0, 0, 0);
    }
    {   // tail k0 = 480, valid k < 500 (W1b zero-padded)
        const int k0 = 480;
        int kb = k0 + oct * 8;
        short8v a;
#pragma unroll
        for (int j = 0; j < 8; ++j)
            a[j] = bfs((kb + j < F_IN) ? xr[kb + j] : 0.f);
        short8v b0 = *reinterpret_cast<const short8v*>(Bl + k0);
        short8v b1 = *reinterpret_cast<const short8v*>(Bl + 16 * KPAD + k0);
        short8v b2 = *reinterpret_cast<const short8v*>(Bl + 32 * KPAD + k0);
        short8v b3 = *reinterpret_cast<const short8v*>(Bl + 48 * KPAD + k0);
        acc0 = __builtin_amdgcn_mfma_f32_16x16x32_bf16(a, b0, acc0, 0, 0, 0);
        acc1 = __builtin_amdgcn_mfma_f32_16x16x32_bf16(a, b1, acc1, 0, 0, 0);
        acc2 = __builtin_amdgcn_mfma_f32_16x16x32_bf16(a, b2, acc2, 0, 0, 0);
        acc3 = __builtin_amdgcn_mfma_f32_16x16x32_bf16(a, b3, acc3, 0, 0, 0);
    }
#pragma unroll
    for (int r = 0; r < 4; ++r) {
        int rr = rowb + oct * 4 + r;
        if (rr < N) {
            float* hp = h1 + (long)rr * HD + l16;
            hp[0]  = acc0[r];
            hp[16] = acc1[r];
            hp[32] = acc2[r];
            hp[48] = acc3[r];
        }
    }
}

// ---------- per-node attention logits (f32 h1) + bf16 copy of h1 ----------
__global__ void k_attlogits1(const float* __restrict__ h1,
        const float* __restrict__ asrc, const float* __restrict__ adst,
        float* __restrict__ als, float* __restrict__ ald,
        ushort* __restrict__ h1b, int N) {
    int t = blockIdx.x * 256 + threadIdx.x;
    if (t >= N * HEADS) return;
    int h = t & 7;
    const float* hp = &h1[(long)t * HID];
    float s1 = 0.f, s2 = 0.f;
    uint w[4];
#pragma unroll
    for (int d = 0; d < 4; d++) {
        float v0 = hp[2 * d], v1 = hp[2 * d + 1];
        s1 += v0 * asrc[h * HID + 2 * d] + v1 * asrc[h * HID + 2 * d + 1];
        s2 += v0 * adst[h * HID + 2 * d] + v1 * adst[h * HID + 2 * d + 1];
        __hip_bfloat16 b0 = __float2bfloat16(v0);
        __hip_bfloat16 b1 = __float2bfloat16(v1);
        w[d] = (uint)*(unsigned short*)&b0 | ((uint)*(unsigned short*)&b1 << 16);
    }
    als[t] = s1; ald[t] = s2;
    *reinterpret_cast<uint4*>(&h1b[(long)t * 8]) = make_uint4(w[0], w[1], w[2], w[3]);
}

// ================= CSR build: two-level counting sort =================
// Buckets of 32 nodes; per-block LDS histograms -> dense global hist ->
// scans -> atomic-free scatter of packed (src<<5|dstlo) -> per-bucket fill.

__global__ __launch_bounds__(256) void k_hist(const void* ei, int E, int N, int nbkt,
        int* __restrict__ ghist, const int* flag) {
    __shared__ int h[NBKT_MAX];
    int tot = E + N;
    int epb = (tot + NBLK_H - 1) / NBLK_H;
    int e0 = blockIdx.x * epb, e1 = min(tot, e0 + epb);
    for (int i = threadIdx.x; i < nbkt; i += 256) h[i] = 0;
    __syncthreads();
    int is64 = *flag;
    for (int e = e0 + threadIdx.x; e < e1; e += 256) {
        int dst = (e < E) ? ld_edge(ei, (long)E + e, is64) : (e - E);
        atomicAdd(&h[dst >> 5], 1);
    }
    __syncthreads();
    for (int i = threadIdx.x; i < nbkt; i += 256)
        ghist[blockIdx.x * nbkt + i] = h[i];
}

__global__ void k_bsum(const int* __restrict__ ghist, int* __restrict__ colsum, int nbkt) {
    int b = blockIdx.x * 256 + threadIdx.x;
    if (b >= nbkt) return;
    int s = 0;
    for (int i = 0; i < NBLK_H; i++) s += ghist[i * nbkt + b];
    colsum[b] = s;
}

__global__ __launch_bounds__(256) void k_bscan2(const int* __restrict__ colsum,
        int* __restrict__ boff, int nbkt) {
    __shared__ int part[256];
    int per = (nbkt + 255) / 256;
    int t = threadIdx.x;
    int lo = t * per, hi = min(nbkt, lo + per);
    int s = 0;
    for (int i = lo; i < hi; i++) s += colsum[i];
    part[t] = s;
    __syncthreads();
    for (int off = 1; off < 256; off <<= 1) {
        int v = (t >= off) ? part[t - off] : 0;
        __syncthreads();
        part[t] += v;
        __syncthreads();
    }
    int run = (t > 0) ? part[t - 1] : 0;
    for (int i = lo; i < hi; i++) { boff[i] = run; run += colsum[i]; }
    if (t == 255) boff[nbkt] = part[255];
}

__global__ void k_bapply(int* __restrict__ ghist, const int* __restrict__ boff, int nbkt) {
    int b = blockIdx.x * 256 + threadIdx.x;
    if (b >= nbkt) return;
    int run = boff[b];
    for (int i = 0; i < NBLK_H; i++) {
        int v = ghist[i * nbkt + b];
        ghist[i * nbkt + b] = run;
        run += v;
    }
}

__global__ __launch_bounds__(256) void k_scatter(const void* ei, int E, int N, int nbkt,
        const int* __restrict__ ghist, uint* __restrict__ pairs, const int* flag) {
    __shared__ int cur[NBKT_MAX];
    int tot = E + N;
    int epb = (tot + NBLK_H - 1) / NBLK_H;
    int e0 = blockIdx.x * epb, e1 = min(tot, e0 + epb);
    for (int i = threadIdx.x; i < nbkt; i += 256) cur[i] = ghist[blockIdx.x * nbkt + i];
    __syncthreads();
    int is64 = *flag;
    for (int e = e0 + threadIdx.x; e < e1; e += 256) {
        int src, dst;
        if (e < E) { src = ld_edge(ei, e, is64); dst = ld_edge(ei, (long)E + e, is64); }
        else { src = dst = e - E; }
        int pos = atomicAdd(&cur[dst >> 5], 1);
        pairs[pos] = ((uint)src << 5) | (uint)(dst & 31);
    }
}

__global__ __launch_bounds__(256) void k_deg2(const uint* __restrict__ pairs,
        const int* __restrict__ boff, int* __restrict__ deg, int N) {
    __shared__ int cnt[32];
    int b = blockIdx.x;
    if (threadIdx.x < 32) cnt[threadIdx.x] = 0;
    __syncthreads();
    int p0 = boff[b], p1 = boff[b + 1];
    for (int p = p0 + threadIdx.x; p < p1; p += 256)
        atomicAdd(&cnt[pairs[p] & 31], 1);
    __syncthreads();
    int n = b * 32 + threadIdx.x;
    if (threadIdx.x < 32 && n < N) deg[n] = cnt[threadIdx.x];
}

__global__ __launch_bounds__(SCB) void k_scan1(const int* deg, int* rowptr, int* bsum, int N) {
    __shared__ int s[SCB];
    int tid = threadIdx.x;
    int i = blockIdx.x * SCB + tid;
    int v = (i < N) ? deg[i] : 0;
    s[tid] = v;
    __syncthreads();
    for (int off = 1; off < SCB; off <<= 1) {
        int tv = (tid >= off) ? s[tid - off] : 0;
        __syncthreads();
        s[tid] += tv;
        __syncthreads();
    }
    if (i < N) rowptr[i] = s[tid] - v;
    if (tid == SCB - 1) bsum[blockIdx.x] = s[tid];
}

__global__ void k_scan2(int* bsum, int* rowptr, int nb, int N) {
    int run = 0;
    for (int i = 0; i < nb; i++) { int v = bsum[i]; bsum[i] = run; run += v; }
    rowptr[N] = run;
}

__global__ void k_scan3(int* rowptr, const int* bsum, int N) {
    int i = blockIdx.x * SCB + threadIdx.x;
    if (i < N) rowptr[i] += bsum[blockIdx.x];
}

__global__ __launch_bounds__(256) void k_fill2(const uint* __restrict__ pairs,
        const int* __restrict__ boff, const int* __restrict__ rowptr,
        int* __restrict__ csr, int N) {
    __shared__ int base[32];
    __shared__ int cur[32];
    int b = blockIdx.x;
    int n0 = b * 32;
    if (threadIdx.x < 32) {
        int n = n0 + threadIdx.x;
        base[threadIdx.x] = (n < N) ? rowptr[n] : 0;
        cur[threadIdx.x] = 0;
    }
    __syncthreads();
    int p0 = boff[b], p1 = boff[b + 1];
    for (int p = p0 + threadIdx.x; p < p1; p += 256) {
        uint v = pairs[p];
        int lo = v & 31;
        int pos = base[lo] + atomicAdd(&cur[lo], 1);
        csr[pos] = (int)(v >> 5);
    }
}

// ---------- Layer-1 pull aggregation + bias + ELU (wave per node, 2-pass) ----------
__global__ __launch_bounds__(256) void k_agg1(const int* __restrict__ rowptr,
        const int* __restrict__ csr, const ushort* __restrict__ h1b,
        const float* __restrict__ als, const float* __restrict__ ald,
        const float* __restrict__ b1, float* __restrict__ hact, int N) {
    int n = blockIdx.x * 4 + (threadIdx.x >> 6);
    if (n >= N) return;
    int lane = threadIdx.x & 63;
    int rs = rowptr[n], re = rowptr[n + 1];

    // ---- pass A: per-head (max, denom). lane = jsub*8 + h
    int hA = lane & 7, jsub = lane >> 3;
    float aldA = ald[n * HEADS + hA];
    float m = -1e30f, sum = 0.f;
    for (int j = rs + jsub; j < re; j += 8) {
        int s = csr[j];
        float e = als[s * HEADS + hA] + aldA;
        e = (e >= 0.f) ? e : NEG * e;
        float nm = fmaxf(m, e);
        float sc = __expf(m - nm);
        sum = sum * sc + __expf(e - nm);
        m = nm;
    }
#pragma unroll
    for (int off = 8; off < 64; off <<= 1) {
        float m2 = __shfl_xor(m, off);
        float s2 = __shfl_xor(sum, off);
        float nm = fmaxf(m, m2);
        sum = sum * __expf(m - nm) + s2 * __expf(m2 - nm);
        m = nm;
    }
    int hB = lane >> 3;
    float mB = __shfl(m, hB);
    float dB = __shfl(sum, hB);
    float aldB = __shfl(aldA, hB);
    float inv = 1.f / (dB + EPSV);

    // ---- pass B: acc = sum_j exp(e_j - mB) * h1b[s_j], unrolled x4
    float a0 = 0.f, a1 = 0.f, a2 = 0.f, a3 = 0.f;
    int j = rs;
    for (; j + 4 <= re; j += 4) {
        int s0 = csr[j], s1 = csr[j + 1], s2 = csr[j + 2], s3 = csr[j + 3];
        float e0 = als[s0 * HEADS + hB] + aldB;
        float e1 = als[s1 * HEADS + hB] + aldB;
        float e2 = als[s2 * HEADS + hB] + aldB;
        float e3 = als[s3 * HEADS + hB] + aldB;
        ushort u0 = h1b[(long)s0 * HD + lane];
        ushort u1 = h1b[(long)s1 * HD + lane];
        ushort u2 = h1b[(long)s2 * HD + lane];
        ushort u3 = h1b[(long)s3 * HD + lane];
        e0 = (e0 >= 0.f) ? e0 : NEG * e0;
        e1 = (e1 >= 0.f) ? e1 : NEG * e1;
        e2 = (e2 >= 0.f) ? e2 : NEG * e2;
        e3 = (e3 >= 0.f) ? e3 : NEG * e3;
        float p0 = __expf(e0 - mB);
        float p1 = __expf(e1 - mB);
        float p2 = __expf(e2 - mB);
        float p3 = __expf(e3 - mB);
        a0 += p0 * __bfloat162float(*(const __hip_bfloat16*)&u0);
        a1 += p1 * __bfloat162float(*(const __hip_bfloat16*)&u1);
        a2 += p2 * __bfloat162float(*(const __hip_bfloat16*)&u2);
        a3 += p3 * __bfloat162float(*(const __hip_bfloat16*)&u3);
    }
    for (; j < re; j++) {
        int s0 = csr[j];
        float e0 = als[s0 * HEADS + hB] + aldB;
        e0 = (e0 >= 0.f) ? e0 : NEG * e0;
        float p0 = __expf(e0 - mB);
        ushort u0 = h1b[(long)s0 * HD + lane];
        a0 += p0 * __bfloat162float(*(const __hip_bfloat16*)&u0);
    }
    float o = ((a0 + a1) + (a2 + a3)) * inv + b1[lane];
    o = (o > 0.f) ? o : __expf(o) - 1.f;   // ELU
    hact[(long)n * HD + lane] = o;
}

// ---------- Layer-2 GEMM [N,64]x[64,3] + logits (wave per node) ----------
__global__ __launch_bounds__(256) void k_gemm2(const float* __restrict__ hact,
        const float* __restrict__ W2, const float* __restrict__ as2,
        const float* __restrict__ ad2, float* __restrict__ h2,
        float* __restrict__ als2, float* __restrict__ ald2, int N) {
    int n = blockIdx.x * 4 + (threadIdx.x >> 6);
    if (n >= N) return;
    int lane = threadIdx.x & 63;
    float hv = hact[(long)n * HD + lane];
    float p0 = hv * W2[lane * CLS + 0];
    float p1 = hv * W2[lane * CLS + 1];
    float p2 = hv * W2[lane * CLS + 2];
#pragma unroll
    for (int off = 32; off > 0; off >>= 1) {
        p0 += __shfl_down(p0, off);
        p1 += __shfl_down(p1, off);
        p2 += __shfl_down(p2, off);
    }
    if (lane == 0) {
        h2[n * CLS + 0] = p0; h2[n * CLS + 1] = p1; h2[n * CLS + 2] = p2;
        als2[n] = p0 * as2[0] + p1 * as2[1] + p2 * as2[2];
        ald2[n] = p0 * ad2[0] + p1 * ad2[1] + p2 * ad2[2];
    }
}

// ---------- Layer-2 pull aggregation + bias + log_softmax ----------
__global__ __launch_bounds__(256) void k_agg2(const int* __restrict__ rowptr,
        const int* __restrict__ csr, const float* __restrict__ h2,
        const float* __restrict__ als2v, const float* __restrict__ ald2v,
        const float* __restrict__ b2, float* __restrict__ out, int N) {
    int n = blockIdx.x * 4 + (threadIdx.x >> 6);
    if (n >= N) return;
    int lane = threadIdx.x & 63;
    float aldv = ald2v[n];
    int rs = rowptr[n], re = rowptr[n + 1];
    float m = -1e30f, sum = 0.f, a0 = 0.f, a1 = 0.f, a2 = 0.f;
    for (int j = rs + lane; j < re; j += 64) {
        int s = csr[j];
        float e = als2v[s] + aldv;
        e = (e >= 0.f) ? e : NEG * e;
        float nm = fmaxf(m, e);
        float sc = __expf(m - nm);
        float p = __expf(e - nm);
        sum = sum * sc + p;
        a0 = a0 * sc + p * h2[s * CLS + 0];
        a1 = a1 * sc + p * h2[s * CLS + 1];
        a2 = a2 * sc + p * h2[s * CLS + 2];
        m = nm;
    }
    float M = m;
#pragma unroll
    for (int off = 1; off < 64; off <<= 1) M = fmaxf(M, __shfl_xor(M, off));
    float sc = __expf(m - M);
    sum *= sc; a0 *= sc; a1 *= sc; a2 *= sc;
#pragma unroll
    for (int off = 1; off < 64; off <<= 1) {
        sum += __shfl_xor(sum, off);
        a0 += __shfl_xor(a0, off);
        a1 += __shfl_xor(a1, off);
        a2 += __shfl_xor(a2, off);
    }
    if (lane == 0) {
        float d = sum + EPSV;
        float v0 = a0 / d + b2[0], v1 = a1 / d + b2[1], v2 = a2 / d + b2[2];
        float mx = fmaxf(v0, fmaxf(v1, v2));
        float se = __expf(v0 - mx) + __expf(v1 - mx) + __expf(v2 - mx);
        float ls = mx + __logf(se);
        out[n * CLS + 0] = v0; out[n * CLS + 1] = v1; out[n * CLS + 2] = v2;
        long o2 = (long)N * CLS;
        out[o2 + n * CLS + 0] = v0 - ls;
        out[o2 + n * CLS + 1] = v1 - ls;
        out[o2 + n * CLS + 2] = v2 - ls;
    }
}

extern "C" void kernel_launch(void* const* d_in, const int* in_sizes, int n_in,
                              void* d_out, int out_size, void* d_ws, size_t ws_size,
                              hipStream_t stream) {
    const float* x   = (const float*)d_in[0];
    const void*  ei  = d_in[1];
    const float* W1  = (const float*)d_in[2];
    const float* as1 = (const float*)d_in[3];
    const float* ad1 = (const float*)d_in[4];
    const float* b1  = (const float*)d_in[5];
    const float* W2  = (const float*)d_in[6];
    const float* as2 = (const float*)d_in[7];
    const float* ad2 = (const float*)d_in[8];
    const float* b2  = (const float*)d_in[9];
    int N = in_sizes[0] / F_IN;
    int E = in_sizes[1] / 2;
    int tot = E + N;
    int nbkt = (N + 31) >> 5;

    char* w = (char*)d_ws;
    auto alloc = [&](size_t bytes) -> char* {
        char* p = w; w += (bytes + 255) & ~size_t(255); return p;
    };
    float*  h1     = (float*)alloc((size_t)N * HD * 4);   // dead after attlogits1
    ushort* h1b    = (ushort*)alloc((size_t)N * HD * 2);
    float*  hact   = (float*)alloc((size_t)N * HD * 4);
    float*  als1   = (float*)alloc((size_t)N * HEADS * 4);
    float*  ald1   = (float*)alloc((size_t)N * HEADS * 4);
    int*    rowptr = (int*)alloc((size_t)(N + 1) * 4);
    int*    deg    = (int*)alloc((size_t)N * 4);
    int nb = (N + SCB - 1) / SCB;
    int*    bsum   = (int*)alloc((size_t)nb * 4);
    int*    csr    = (int*)alloc((size_t)tot * 4);
    float*  h2     = (float*)alloc((size_t)N * CLS * 4);
    float*  als2   = (float*)alloc((size_t)N * 4);
    float*  ald2   = (float*)alloc((size_t)N * 4);
    ushort* W1b    = (ushort*)alloc((size_t)HD * KPAD * 2);
    int*    flag   = (int*)alloc(256);

    // CSR-build scratch aliases h1 (h1 is dead once attlogits1 has run,
    // and the build kernels are ordered after it on the same stream).
    char* ov = (char*)h1;
    uint* pairs  = (uint*)ov;                      ov += ((size_t)tot * 4 + 255) & ~size_t(255);
    int*  ghist  = (int*)ov;                       ov += ((size_t)NBLK_H * nbkt * 4 + 255) & ~size_t(255);
    int*  colsum = (int*)ov;                       ov += ((size_t)nbkt * 4 + 255) & ~size_t(255);
    int*  boff   = (int*)ov;                       ov += ((size_t)(nbkt + 1) * 4 + 255) & ~size_t(255);

    k_detect<<<1, 1, 0, stream>>>((const int*)ei, flag);
    k_prepW<<<(HD * KPAD + 255) / 256, 256, 0, stream>>>(W1, W1b);
    k_gemm1<<<(N + 63) / 64, 256, 0, stream>>>(x, W1b, h1, N);
    k_attlogits1<<<(N * HEADS + 255) / 256, 256, 0, stream>>>(h1, as1, ad1, als1, ald1, h1b, N);
    // ---- CSR build (h1 now dead; scratch aliases it)
    k_hist<<<NBLK_H, 256, 0, stream>>>(ei, E, N, nbkt, ghist, flag);
    k_bsum<<<(nbkt + 255) / 256, 256, 0, stream>>>(ghist, colsum, nbkt);
    k_bscan2<<<1, 256, 0, stream>>>(colsum, boff, nbkt);
    k_bapply<<<(nbkt + 255) / 256, 256, 0, stream>>>(ghist, boff, nbkt);
    k_scatter<<<NBLK_H, 256, 0, stream>>>(ei, E, N, nbkt, ghist, pairs, flag);
    k_deg2<<<nbkt, 256, 0, stream>>>(pairs, boff, deg, N);
    k_scan1<<<nb, SCB, 0, stream>>>(deg, rowptr, bsum, N);
    k_scan2<<<1, 1, 0, stream>>>(bsum, rowptr, nb, N);
    k_scan3<<<nb, SCB, 0, stream>>>(rowptr, bsum, N);
    k_fill2<<<nbkt, 256, 0, stream>>>(pairs, boff, rowptr, csr, N);
    // ---- aggregation / layer 2
    k_agg1<<<(N + 3) / 4, 256, 0, stream>>>(rowptr, csr, h1b, als1, ald1, b1, hact, N);
    k_gemm2<<<(N + 3) / 4, 256, 0, stream>>>(hact, W2, as2, ad2, h2, als2, ald2, N);
    k_agg2<<<(N + 3) / 4, 256, 0, stream>>>(rowptr, csr, h2, als2, ald2, b2, (float*)d_out, N);
}

// Round 5
// 454.822 us; speedup vs baseline: 2.0928x; 1.1480x over previous
//
#include <hip/hip_runtime.h>
#include <hip/hip_bf16.h>

// GAT 2-layer forward on MI355X.
// CSR-by-dst build via two-level counting sort (no global atomics, dense
// writes) + single-pass pull aggregation (no-max softmax, logits computed
// once per edge-head, bpermute broadcast).
// GEMM1: LDS-free bf16 MFMA (16x16x32) straight from global x.

#define F_IN 500
#define HEADS 8
#define HID 8
#define HD 64   // HEADS*HID
#define CLS 3
#define NEG 0.2f
#define EPSV 1e-16f
#define KPAD 512
#define SCB 512
#define LOG2E 1.44269504088896340736f

#define NBLK_H 128     // blocks in hist/scatter passes
#define NBKT_MAX 3136  // >= ceil(N/32)

typedef __attribute__((ext_vector_type(8))) short short8v;   // 8 bf16
typedef __attribute__((ext_vector_type(4))) float f32x4;

__device__ inline short bfs(float v) {
    __hip_bfloat16 b = __float2bfloat16(v);
    return *(short*)&b;
}

// ---------- edge_index dtype detection (int32 vs int64 little-endian) ----------
__global__ void k_detect(const int* ei, int* flag) {
    int z = 0;
    for (int i = 1; i < 16; i += 2) z += (ei[i] == 0) ? 1 : 0;
    *flag = (z == 8) ? 1 : 0;
}

__device__ inline int ld_edge(const void* ei, long idx, int is64) {
    return is64 ? (int)((const long long*)ei)[idx] : ((const int*)ei)[idx];
}

// ---------- W1 -> bf16, transposed [c][k] with k zero-padded to 512 ----------
__global__ void k_prepW(const float* __restrict__ W1, ushort* __restrict__ W1b) {
    int i = blockIdx.x * 256 + threadIdx.x;
    if (i >= HD * KPAD) return;
    int c = i >> 9, k = i & (KPAD - 1);
    float v = (k < F_IN) ? W1[k * HD + c] : 0.f;
    __hip_bfloat16 b = __float2bfloat16(v);
    W1b[i] = *(ushort*)&b;
}

// ---------- Layer-1 GEMM: h1[N,64] = x[N,500] @ W1[500,64], bf16 MFMA ----------
__global__ __launch_bounds__(256) void k_gemm1(const float* __restrict__ x,
        const ushort* __restrict__ W1b, float* __restrict__ h1, int N) {
    int lane = threadIdx.x & 63;
    int w = threadIdx.x >> 6;
    int l16 = lane & 15, oct = lane >> 4;
    int rowb = blockIdx.x * 64 + w * 16;
    int row = rowb + l16;
    int rowc = (row < N) ? row : (N - 1);
    const float* xr = x + (long)rowc * F_IN;

    f32x4 acc0 = {0.f, 0.f, 0.f, 0.f};
    f32x4 acc1 = {0.f, 0.f, 0.f, 0.f};
    f32x4 acc2 = {0.f, 0.f, 0.f, 0.f};
    f32x4 acc3 = {0.f, 0.f, 0.f, 0.f};

    const ushort* Bl = W1b + (size_t)l16 * KPAD + oct * 8;

#pragma unroll
    for (int ks = 0; ks < 15; ++ks) {
        const int k0 = ks * 32;
        short8v b0 = *reinterpret_cast<const short8v*>(Bl + k0);
        short8v b1 = *reinterpret_cast<const short8v*>(Bl + 16 * KPAD + k0);
        short8v b2 = *reinterpret_cast<const short8v*>(Bl + 32 * KPAD + k0);
        short8v b3 = *reinterpret_cast<const short8v*>(Bl + 48 * KPAD + k0);
        float4 x0 = *reinterpret_cast<const float4*>(xr + k0 + oct * 8);
        float4 x1 = *reinterpret_cast<const float4*>(xr + k0 + oct * 8 + 4);
        short8v a;
        a[0] = bfs(x0.x); a[1] = bfs(x0.y); a[2] = bfs(x0.z); a[3] = bfs(x0.w);
        a[4] = bfs(x1.x); a[5] = bfs(x1.y); a[6] = bfs(x1.z); a[7] = bfs(x1.w);
        acc0 = __builtin_amdgcn_mfma_f32_16x16x32_bf16(a, b0, acc0, 0, 0, 0);
        acc1 = __builtin_amdgcn_mfma_f32_16x16x32_bf16(a, b1, acc1, 0, 0, 0);
        acc2 = __builtin_amdgcn_mfma_f32_16x16x32_bf16(a, b2, acc2, 0, 0, 0);
        acc3 = __builtin_amdgcn_mfma_f32_16x16x32_bf16(a, b3, acc3, 0, 0, 0);
    }
    {   // tail k0 = 480, valid k < 500 (W1b zero-padded)
        const int k0 = 480;
        int kb = k0 + oct * 8;
        short8v a;
#pragma unroll
        for (int j = 0; j < 8; ++j)
            a[j] = bfs((kb + j < F_IN) ? xr[kb + j] : 0.f);
        short8v b0 = *reinterpret_cast<const short8v*>(Bl + k0);
        short8v b1 = *reinterpret_cast<const short8v*>(Bl + 16 * KPAD + k0);
        short8v b2 = *reinterpret_cast<const short8v*>(Bl + 32 * KPAD + k0);
        short8v b3 = *reinterpret_cast<const short8v*>(Bl + 48 * KPAD + k0);
        acc0 = __builtin_amdgcn_mfma_f32_16x16x32_bf16(a, b0, acc0, 0, 0, 0);
        acc1 = __builtin_amdgcn_mfma_f32_16x16x32_bf16(a, b1, acc1, 0, 0, 0);
        acc2 = __builtin_amdgcn_mfma_f32_16x16x32_bf16(a, b2, acc2, 0, 0, 0);
        acc3 = __builtin_amdgcn_mfma_f32_16x16x32_bf16(a, b3, acc3, 0, 0, 0);
    }
#pragma unroll
    for (int r = 0; r < 4; ++r) {
        int rr = rowb + oct * 4 + r;
        if (rr < N) {
            float* hp = h1 + (long)rr * HD + l16;
            hp[0]  = acc0[r];
            hp[16] = acc1[r];
            hp[32] = acc2[r];
            hp[48] = acc3[r];
        }
    }
}

// ---------- per-node attention logits (prescaled by log2(e)) + bf16 h1 copy ----------
__global__ void k_attlogits1(const float* __restrict__ h1,
        const float* __restrict__ asrc, const float* __restrict__ adst,
        float* __restrict__ als, float* __restrict__ ald,
        ushort* __restrict__ h1b, int N) {
    int t = blockIdx.x * 256 + threadIdx.x;
    if (t >= N * HEADS) return;
    int h = t & 7;
    const float* hp = &h1[(long)t * HID];
    float s1 = 0.f, s2 = 0.f;
    uint w[4];
#pragma unroll
    for (int d = 0; d < 4; d++) {
        float v0 = hp[2 * d], v1 = hp[2 * d + 1];
        s1 += v0 * asrc[h * HID + 2 * d] + v1 * asrc[h * HID + 2 * d + 1];
        s2 += v0 * adst[h * HID + 2 * d] + v1 * adst[h * HID + 2 * d + 1];
        __hip_bfloat16 b0 = __float2bfloat16(v0);
        __hip_bfloat16 b1 = __float2bfloat16(v1);
        w[d] = (uint)*(unsigned short*)&b0 | ((uint)*(unsigned short*)&b1 << 16);
    }
    als[t] = s1 * LOG2E; ald[t] = s2 * LOG2E;   // exp2 domain
    *reinterpret_cast<uint4*>(&h1b[(long)t * 8]) = make_uint4(w[0], w[1], w[2], w[3]);
}

// ================= CSR build: two-level counting sort =================

__global__ __launch_bounds__(256) void k_hist(const void* ei, int E, int N, int nbkt,
        int* __restrict__ ghist, const int* flag) {
    __shared__ int h[NBKT_MAX];
    int tot = E + N;
    int epb = (tot + NBLK_H - 1) / NBLK_H;
    int e0 = blockIdx.x * epb, e1 = min(tot, e0 + epb);
    for (int i = threadIdx.x; i < nbkt; i += 256) h[i] = 0;
    __syncthreads();
    int is64 = *flag;
    for (int e = e0 + threadIdx.x; e < e1; e += 256) {
        int dst = (e < E) ? ld_edge(ei, (long)E + e, is64) : (e - E);
        atomicAdd(&h[dst >> 5], 1);
    }
    __syncthreads();
    for (int i = threadIdx.x; i < nbkt; i += 256)
        ghist[blockIdx.x * nbkt + i] = h[i];
}

__global__ void k_bsum(const int* __restrict__ ghist, int* __restrict__ colsum, int nbkt) {
    int b = blockIdx.x * 256 + threadIdx.x;
    if (b >= nbkt) return;
    int s = 0;
    for (int i = 0; i < NBLK_H; i++) s += ghist[i * nbkt + b];
    colsum[b] = s;
}

__global__ __launch_bounds__(256) void k_bscan2(const int* __restrict__ colsum,
        int* __restrict__ boff, int nbkt) {
    __shared__ int part[256];
    int per = (nbkt + 255) / 256;
    int t = threadIdx.x;
    int lo = t * per, hi = min(nbkt, lo + per);
    int s = 0;
    for (int i = lo; i < hi; i++) s += colsum[i];
    part[t] = s;
    __syncthreads();
    for (int off = 1; off < 256; off <<= 1) {
        int v = (t >= off) ? part[t - off] : 0;
        __syncthreads();
        part[t] += v;
        __syncthreads();
    }
    int run = (t > 0) ? part[t - 1] : 0;
    for (int i = lo; i < hi; i++) { boff[i] = run; run += colsum[i]; }
    if (t == 255) boff[nbkt] = part[255];
}

__global__ void k_bapply(int* __restrict__ ghist, const int* __restrict__ boff, int nbkt) {
    int b = blockIdx.x * 256 + threadIdx.x;
    if (b >= nbkt) return;
    int run = boff[b];
    for (int i = 0; i < NBLK_H; i++) {
        int v = ghist[i * nbkt + b];
        ghist[i * nbkt + b] = run;
        run += v;
    }
}

__global__ __launch_bounds__(256) void k_scatter(const void* ei, int E, int N, int nbkt,
        const int* __restrict__ ghist, uint* __restrict__ pairs, const int* flag) {
    __shared__ int cur[NBKT_MAX];
    int tot = E + N;
    int epb = (tot + NBLK_H - 1) / NBLK_H;
    int e0 = blockIdx.x * epb, e1 = min(tot, e0 + epb);
    for (int i = threadIdx.x; i < nbkt; i += 256) cur[i] = ghist[blockIdx.x * nbkt + i];
    __syncthreads();
    int is64 = *flag;
    for (int e = e0 + threadIdx.x; e < e1; e += 256) {
        int src, dst;
        if (e < E) { src = ld_edge(ei, e, is64); dst = ld_edge(ei, (long)E + e, is64); }
        else { src = dst = e - E; }
        int pos = atomicAdd(&cur[dst >> 5], 1);
        pairs[pos] = ((uint)src << 5) | (uint)(dst & 31);
    }
}

__global__ __launch_bounds__(256) void k_deg2(const uint* __restrict__ pairs,
        const int* __restrict__ boff, int* __restrict__ deg, int N) {
    __shared__ int cnt[32];
    int b = blockIdx.x;
    if (threadIdx.x < 32) cnt[threadIdx.x] = 0;
    __syncthreads();
    int p0 = boff[b], p1 = boff[b + 1];
    for (int p = p0 + threadIdx.x; p < p1; p += 256)
        atomicAdd(&cnt[pairs[p] & 31], 1);
    __syncthreads();
    int n = b * 32 + threadIdx.x;
    if (threadIdx.x < 32 && n < N) deg[n] = cnt[threadIdx.x];
}

__global__ __launch_bounds__(SCB) void k_scan1(const int* deg, int* rowptr, int* bsum, int N) {
    __shared__ int s[SCB];
    int tid = threadIdx.x;
    int i = blockIdx.x * SCB + tid;
    int v = (i < N) ? deg[i] : 0;
    s[tid] = v;
    __syncthreads();
    for (int off = 1; off < SCB; off <<= 1) {
        int tv = (tid >= off) ? s[tid - off] : 0;
        __syncthreads();
        s[tid] += tv;
        __syncthreads();
    }
    if (i < N) rowptr[i] = s[tid] - v;
    if (tid == SCB - 1) bsum[blockIdx.x] = s[tid];
}

__global__ void k_scan2(int* bsum, int* rowptr, int nb, int N) {
    int run = 0;
    for (int i = 0; i < nb; i++) { int v = bsum[i]; bsum[i] = run; run += v; }
    rowptr[N] = run;
}

__global__ void k_scan3(int* rowptr, const int* bsum, int N) {
    int i = blockIdx.x * SCB + threadIdx.x;
    if (i < N) rowptr[i] += bsum[blockIdx.x];
}

__global__ __launch_bounds__(256) void k_fill2(const uint* __restrict__ pairs,
        const int* __restrict__ boff, const int* __restrict__ rowptr,
        int* __restrict__ csr, int N) {
    __shared__ int base[32];
    __shared__ int cur[32];
    int b = blockIdx.x;
    int n0 = b * 32;
    if (threadIdx.x < 32) {
        int n = n0 + threadIdx.x;
        base[threadIdx.x] = (n < N) ? rowptr[n] : 0;
        cur[threadIdx.x] = 0;
    }
    __syncthreads();
    int p0 = boff[b], p1 = boff[b + 1];
    for (int p = p0 + threadIdx.x; p < p1; p += 256) {
        uint v = pairs[p];
        int lo = v & 31;
        int pos = base[lo] + atomicAdd(&cur[lo], 1);
        csr[pos] = (int)(v >> 5);
    }
}

// ---------- Layer-1 pull aggregation (single pass, no-max softmax) ----------
// Wave per node. Per 8-edge group: lane l computes logit for edge-slot (l>>3),
// head (l&7) -> one exp2 per edge-head across the wave. Accumulate side:
// p broadcast via ds_bpermute, src index via readlane (SGPR gather base).
__global__ __launch_bounds__(256) void k_agg1(const int* __restrict__ rowptr,
        const int* __restrict__ csr, const ushort* __restrict__ h1b,
        const float* __restrict__ als, const float* __restrict__ ald,
        const float* __restrict__ b1, float* __restrict__ hact, int N) {
    int n = blockIdx.x * 4 + (threadIdx.x >> 6);
    if (n >= N) return;
    int lane = threadIdx.x & 63;
    int rs = rowptr[n], re = rowptr[n + 1];
    int h = lane & 7;        // head (logit role)
    int es = lane >> 3;      // edge slot (logit role); also my head (accum role)
    float aldh = ald[n * HEADS + h];
    int bpa = es * 4;        // bpermute byte addr base: source lane eg*8 + (lane>>3)
    float acc = 0.f, den = 0.f;

    for (int jb = rs; jb < re; jb += 8) {
        int eidx = jb + es;
        bool valid = (eidx < re);
        int s_own = valid ? csr[eidx] : 0;
        float e = valid ? (als[s_own * HEADS + h] + aldh) : -1e30f;
        e = fmaxf(e, NEG * e);          // leaky relu (scale-invariant, log2 domain)
        float p = exp2f(e);             // v_exp_f32
#pragma unroll
        for (int eg = 0; eg < 8; ++eg) {
            float pe = __int_as_float(
                __builtin_amdgcn_ds_bpermute(bpa + eg * 32, __float_as_int(p)));
            int se = __builtin_amdgcn_readlane(s_own, eg * 8);
            ushort u = h1b[(long)se * HD + lane];
            acc += pe * __bfloat162float(*(const __hip_bfloat16*)&u);
            den += pe;
        }
    }
    float o = acc / (den + EPSV) + b1[lane];
    o = (o > 0.f) ? o : __expf(o) - 1.f;   // ELU
    hact[(long)n * HD + lane] = o;
}

// ---------- Layer-2 GEMM [N,64]x[64,3] + logits (wave per node) ----------
__global__ __launch_bounds__(256) void k_gemm2(const float* __restrict__ hact,
        const float* __restrict__ W2, const float* __restrict__ as2,
        const float* __restrict__ ad2, float* __restrict__ h2,
        float* __restrict__ als2, float* __restrict__ ald2, int N) {
    int n = blockIdx.x * 4 + (threadIdx.x >> 6);
    if (n >= N) return;
    int lane = threadIdx.x & 63;
    float hv = hact[(long)n * HD + lane];
    float p0 = hv * W2[lane * CLS + 0];
    float p1 = hv * W2[lane * CLS + 1];
    float p2 = hv * W2[lane * CLS + 2];
#pragma unroll
    for (int off = 32; off > 0; off >>= 1) {
        p0 += __shfl_down(p0, off);
        p1 += __shfl_down(p1, off);
        p2 += __shfl_down(p2, off);
    }
    if (lane == 0) {
        h2[n * CLS + 0] = p0; h2[n * CLS + 1] = p1; h2[n * CLS + 2] = p2;
        als2[n] = p0 * as2[0] + p1 * as2[1] + p2 * as2[2];
        ald2[n] = p0 * ad2[0] + p1 * ad2[1] + p2 * ad2[2];
    }
}

// ---------- Layer-2 pull aggregation + bias + log_softmax ----------
__global__ __launch_bounds__(256) void k_agg2(const int* __restrict__ rowptr,
        const int* __restrict__ csr, const float* __restrict__ h2,
        const float* __restrict__ als2v, const float* __restrict__ ald2v,
        const float* __restrict__ b2, float* __restrict__ out, int N) {
    int n = blockIdx.x * 4 + (threadIdx.x >> 6);
    if (n >= N) return;
    int lane = threadIdx.x & 63;
    float aldv = ald2v[n];
    int rs = rowptr[n], re = rowptr[n + 1];
    float m = -1e30f, sum = 0.f, a0 = 0.f, a1 = 0.f, a2 = 0.f;
    for (int j = rs + lane; j < re; j += 64) {
        int s = csr[j];
        float e = als2v[s] + aldv;
        e = (e >= 0.f) ? e : NEG * e;
        float nm = fmaxf(m, e);
        float sc = __expf(m - nm);
        float p = __expf(e - nm);
        sum = sum * sc + p;
        a0 = a0 * sc + p * h2[s * CLS + 0];
        a1 = a1 * sc + p * h2[s * CLS + 1];
        a2 = a2 * sc + p * h2[s * CLS + 2];
        m = nm;
    }
    float M = m;
#pragma unroll
    for (int off = 1; off < 64; off <<= 1) M = fmaxf(M, __shfl_xor(M, off));
    float sc = __expf(m - M);
    sum *= sc; a0 *= sc; a1 *= sc; a2 *= sc;
#pragma unroll
    for (int off = 1; off < 64; off <<= 1) {
        sum += __shfl_xor(sum, off);
        a0 += __shfl_xor(a0, off);
        a1 += __shfl_xor(a1, off);
        a2 += __shfl_xor(a2, off);
    }
    if (lane == 0) {
        float d = sum + EPSV;
        float v0 = a0 / d + b2[0], v1 = a1 / d + b2[1], v2 = a2 / d + b2[2];
        float mx = fmaxf(v0, fmaxf(v1, v2));
        float se = __expf(v0 - mx) + __expf(v1 - mx) + __expf(v2 - mx);
        float ls = mx + __logf(se);
        out[n * CLS + 0] = v0; out[n * CLS + 1] = v1; out[n * CLS + 2] = v2;
        long o2 = (long)N * CLS;
        out[o2 + n * CLS + 0] = v0 - ls;
        out[o2 + n * CLS + 1] = v1 - ls;
        out[o2 + n * CLS + 2] = v2 - ls;
    }
}

extern "C" void kernel_launch(void* const* d_in, const int* in_sizes, int n_in,
                              void* d_out, int out_size, void* d_ws, size_t ws_size,
                              hipStream_t stream) {
    const float* x   = (const float*)d_in[0];
    const void*  ei  = d_in[1];
    const float* W1  = (const float*)d_in[2];
    const float* as1 = (const float*)d_in[3];
    const float* ad1 = (const float*)d_in[4];
    const float* b1  = (const float*)d_in[5];
    const float* W2  = (const float*)d_in[6];
    const float* as2 = (const float*)d_in[7];
    const float* ad2 = (const float*)d_in[8];
    const float* b2  = (const float*)d_in[9];
    int N = in_sizes[0] / F_IN;
    int E = in_sizes[1] / 2;
    int tot = E + N;
    int nbkt = (N + 31) >> 5;

    char* w = (char*)d_ws;
    auto alloc = [&](size_t bytes) -> char* {
        char* p = w; w += (bytes + 255) & ~size_t(255); return p;
    };
    float*  h1     = (float*)alloc((size_t)N * HD * 4);   // dead after attlogits1
    ushort* h1b    = (ushort*)alloc((size_t)N * HD * 2);
    float*  hact   = (float*)alloc((size_t)N * HD * 4);
    float*  als1   = (float*)alloc((size_t)N * HEADS * 4);
    float*  ald1   = (float*)alloc((size_t)N * HEADS * 4);
    int*    rowptr = (int*)alloc((size_t)(N + 1) * 4);
    int*    deg    = (int*)alloc((size_t)N * 4);
    int nb = (N + SCB - 1) / SCB;
    int*    bsum   = (int*)alloc((size_t)nb * 4);
    int*    csr    = (int*)alloc((size_t)tot * 4);
    float*  h2     = (float*)alloc((size_t)N * CLS * 4);
    float*  als2   = (float*)alloc((size_t)N * 4);
    float*  ald2   = (float*)alloc((size_t)N * 4);
    ushort* W1b    = (ushort*)alloc((size_t)HD * KPAD * 2);
    int*    flag   = (int*)alloc(256);

    // CSR-build scratch aliases h1 (dead after attlogits1, same-stream ordered).
    char* ov = (char*)h1;
    uint* pairs  = (uint*)ov;                      ov += ((size_t)tot * 4 + 255) & ~size_t(255);
    int*  ghist  = (int*)ov;                       ov += ((size_t)NBLK_H * nbkt * 4 + 255) & ~size_t(255);
    int*  colsum = (int*)ov;                       ov += ((size_t)nbkt * 4 + 255) & ~size_t(255);
    int*  boff   = (int*)ov;                       ov += ((size_t)(nbkt + 1) * 4 + 255) & ~size_t(255);

    k_detect<<<1, 1, 0, stream>>>((const int*)ei, flag);
    k_prepW<<<(HD * KPAD + 255) / 256, 256, 0, stream>>>(W1, W1b);
    k_gemm1<<<(N + 63) / 64, 256, 0, stream>>>(x, W1b, h1, N);
    k_attlogits1<<<(N * HEADS + 255) / 256, 256, 0, stream>>>(h1, as1, ad1, als1, ald1, h1b, N);
    // ---- CSR build
    k_hist<<<NBLK_H, 256, 0, stream>>>(ei, E, N, nbkt, ghist, flag);
    k_bsum<<<(nbkt + 255) / 256, 256, 0, stream>>>(ghist, colsum, nbkt);
    k_bscan2<<<1, 256, 0, stream>>>(colsum, boff, nbkt);
    k_bapply<<<(nbkt + 255) / 256, 256, 0, stream>>>(ghist, boff, nbkt);
    k_scatter<<<NBLK_H, 256, 0, stream>>>(ei, E, N, nbkt, ghist, pairs, flag);
    k_deg2<<<nbkt, 256, 0, stream>>>(pairs, boff, deg, N);
    k_scan1<<<nb, SCB, 0, stream>>>(deg, rowptr, bsum, N);
    k_scan2<<<1, 1, 0, stream>>>(bsum, rowptr, nb, N);
    k_scan3<<<nb, SCB, 0, stream>>>(rowptr, bsum, N);
    k_fill2<<<nbkt, 256, 0, stream>>>(pairs, boff, rowptr, csr, N);
    // ---- aggregation / layer 2
    k_agg1<<<(N + 3) / 4, 256, 0, stream>>>(rowptr, csr, h1b, als1, ald1, b1, hact, N);
    k_gemm2<<<(N + 3) / 4, 256, 0, stream>>>(hact, W2, as2, ad2, h2, als2, ald2, N);
    k_agg2<<<(N + 3) / 4, 256, 0, stream>>>(rowptr, csr, h2, als2, ald2, b2, (float*)d_out, N);
}